// Round 7
// baseline (266.136 us; speedup 1.0000x reference)
//
#include <hip/hip_runtime.h>

#define BB 64
#define TT 4096
#define KK 48
#define UST 56              // Ubuf col stride (bf16): 112 B. MUST be mult of 8 elems
                            // (16 B): r5's UST=58 misaligned ds_read_b128 -> 3.6x slower.
#define PST 56              // phase LDS col stride (bf16)
#define WS_LS_OFF 16384
#define WS_U_OFF 32768
#define SEGBYTES 4608       // compact: 48 rows x 48 col-stride x bf16
#define SEGELEMS 2304

typedef __bf16 bf16_t;
typedef bf16_t bf16x8 __attribute__((ext_vector_type(8)));
typedef float f32x4 __attribute__((ext_vector_type(4)));
typedef float f32x16 __attribute__((ext_vector_type(16)));

__device__ __forceinline__ float fexp(float x) {   // natural exp
    return __builtin_amdgcn_exp2f(x * 1.4426950408889634f);
}
__device__ __forceinline__ float flog2(float x) { return __builtin_amdgcn_logf(x); }
__device__ __forceinline__ float rdlanef(float v, int l) {
    return __int_as_float(__builtin_amdgcn_readlane(__float_as_int(v), l));
}
__device__ __forceinline__ unsigned int bf16bits(float f) {
    return (unsigned int)__builtin_bit_cast(unsigned short, (bf16_t)f);
}
__device__ __forceinline__ float bf2f(bf16_t h) {
    return __uint_as_float(((unsigned int)__builtin_bit_cast(unsigned short, h)) << 16);
}
// pack two fp32 -> bf16x2 by truncation (1 v_perm_b32); lo in low half
__device__ __forceinline__ unsigned int pktrunc(float lo, float hi) {
    return __builtin_amdgcn_perm(__float_as_uint(hi), __float_as_uint(lo), 0x07060302u);
}

// ============ fused: 8-wave block = 2 parallel half-chains + in-block compose ====
// r7: each block runs TWO independent 128-step sub-chains (waves 0-3 = sub 0:
// chunks [0,nch/2) with exf[0]/Ubuf[0]; waves 4-7 = sub 1: chunks [nch/2,nch))
// then composes U_seg = U_B x U_A in-block (one extra MFMA step with A-frags =
// U_B read from a row-major LDS buffer overlaid on dead exf[1]). Per-wave chain
// code is byte-identical to r6's verified version. Critical path halves
// (256 -> 128 steps), occupancy 16 -> 32 waves/CU (grid-capped before; LDS
// 37.5 KB -> still 4 blocks/CU). Workspace layout/fold8/final unchanged.
// (512,8): VGPR budget 64 (chain code allocs 48 at this budget, r6 verified).
__global__ __launch_bounds__(512, 8) void fused_kernel(
    const float* __restrict__ y_true, const float* __restrict__ y_pred,
    const float* __restrict__ trans, float* __restrict__ ws_target,
    int* __restrict__ ws_ls, bf16_t* __restrict__ ws_u, int nseg) {
    const int s = blockIdx.x, b = blockIdx.y;
    const int seglen = TT / nseg;
    const int nch_sub = seglen / 128;       // chunks per sub-chain (>=1 for nseg<=32)
    const int tid = threadIdx.x;
    const int w = tid >> 6;                 // 0..7
    const int sub = w >> 2;                 // sub-chain id 0/1
    const int wl = w & 3;                   // role within sub-chain: 0-2 chain, 3 producer
    const int lane = tid & 63;
    const int q = lane >> 4;
    const int n = lane & 15;
    const int ncol = 16 * wl + n;

    __shared__ __align__(16) float4 exf[2][64 * 13];          // fp32 ex per sub-chain
    __shared__ __align__(16) bf16_t Ubuf[2][48 * UST + 16];   // U state per sub-chain
    __shared__ unsigned long long pb[2];
    __shared__ int lsbA[4], lsbB[4];
    __shared__ float scpart[2];

    // A fragments (chain waves of both subs): E^T zero-padded in K.
    bf16x8 afrag[3][2];
    if (wl < 3) {
#pragma unroll
        for (int mt = 0; mt < 3; mt++) {
#pragma unroll
            for (int ks = 0; ks < 2; ks++) {
                bf16x8 f;
#pragma unroll
                for (int j = 0; j < 8; j++) {
                    int k = 32 * ks + 8 * q + j;
                    float v = (k < KK) ? fexp(trans[k * KK + 16 * mt + n]) : 0.0f;
                    f[j] = (bf16_t)v;
                }
                afrag[mt][ks] = f;
            }
        }
    }

    {   // zero both Ubufs then identity diags
        uint4* p = (uint4*)&Ubuf[0][0];
        const int nq = 2 * (48 * UST + 16) / 8;
        for (int i = tid; i < nq; i += 512) p[i] = make_uint4(0, 0, 0, 0);
    }
    __syncthreads();
    if (tid < KK) {
        Ubuf[0][tid * UST + tid] = (bf16_t)1.0f;
        Ubuf[1][tid * UST + tid] = (bf16_t)1.0f;
    }

    const bf16_t* bptr0 = &Ubuf[sub][ncol * UST + 8 * q];
    const bf16_t* bptr1 = &Ubuf[sub][ncol * UST + 32 + 8 * q];
    bf16_t* wp0 = &Ubuf[sub][ncol * UST + 0 + 4 * q];
    bf16_t* wp1 = &Ubuf[sub][ncol * UST + 16 + 4 * q];
    bf16_t* wp2 = &Ubuf[sub][ncol * UST + 32 + 4 * q];

    f32x4 z4 = {0.0f, 0.0f, 0.0f, 0.0f};
    int ls = 0;
    int cnt = 0;          // unmasked steps since last rescale (wave-uniform)
    float sc_acc = 0.0f;  // producers: scores accumulator

    for (int ch = 0; ch < nch_sub; ch++) {
        __syncthreads();                     // previous exf fully consumed
        if (wl == 3) {
            // ---- producer + scores: lane = local timestep ----
            const int gch = sub * nch_sub + ch;
            const int t0c = s * seglen + gch * 64;
            const size_t rowbase = ((size_t)b * TT + t0c + lane) * KK;
            const float4* yp4 = (const float4*)(y_pred + rowbase);
            const float4* yt4 = (const float4*)(y_true + rowbase);
            float dot = 0.0f, labf = 0.0f, pmin = 1e30f;
            float4* exrow = &exf[sub][lane * 13];
#pragma unroll 4
            for (int g = 0; g < 12; g++) {
                float4 p = yp4[g];
                float4 a = yt4[g];
                dot = fmaf(a.x, p.x, fmaf(a.y, p.y, fmaf(a.z, p.z, fmaf(a.w, p.w, dot))));
                float e0 = (float)(4 * g);
                labf = fmaf(a.x, e0, fmaf(a.y, e0 + 1.0f, fmaf(a.z, e0 + 2.0f, fmaf(a.w, e0 + 3.0f, labf))));
                pmin = fminf(pmin, fminf(fminf(p.x, p.y), fminf(p.z, p.w)));
                exrow[g] = make_float4(fexp(p.x), fexp(p.y), fexp(p.z), fexp(p.w));
            }
            bool mt_ok = pmin > -1e6f;
            unsigned long long bal = __ballot(mt_ok);
            if (lane == 0) pb[sub] = bal;

            // boundary row t0c+64 (label+mask), lanes 0..11 partials
            float labB = 0.0f, pmB = 1e30f;
            const bool hasB = (t0c + 64 < TT);
            if (hasB && lane < 12) {
                const size_t bdbase = ((size_t)b * TT + t0c + 64) * KK;
                float4 a = ((const float4*)(y_true + bdbase))[lane];
                float4 p = ((const float4*)(y_pred + bdbase))[lane];
                float e0 = (float)(4 * lane);
                labB = fmaf(a.x, e0, fmaf(a.y, e0 + 1.0f, fmaf(a.z, e0 + 2.0f, a.w * (e0 + 3.0f))));
                pmB = fminf(fminf(p.x, p.y), fminf(p.z, p.w));
            }
#pragma unroll
            for (int off = 1; off < 16; off <<= 1) {
                labB += __shfl_xor(labB, off);
                pmB = fminf(pmB, __shfl_xor(pmB, off));
            }
            int labB_i = (int)(rdlanef(labB, 0) + 0.5f);
            float mB = (hasB && rdlanef(pmB, 0) > -1e6f) ? 1.0f : 0.0f;

            int labt = (int)(labf + 0.5f);
            float mft = mt_ok ? 1.0f : 0.0f;
            int lnx = __shfl(labt, (lane + 1) & 63);
            float mnx = __shfl(mft, (lane + 1) & 63);
            if (lane == 63) { lnx = labB_i; mnx = mB; }
            sc_acc += mft * dot + mft * mnx * trans[labt * KK + lnx];
        }
        __syncthreads();
        if (wl < 3) {
            const unsigned long long mk = pb[sub];
            const int tt0 = (s == 0 && sub == 0 && ch == 0) ? 1 : 0;
            for (int tt = tt0; tt < 64; tt++) {
                if (!((mk >> tt) & 1ull)) continue;

                bf16x8 bf0 = __builtin_bit_cast(bf16x8, *(const uint4*)bptr0);
                bf16x8 bf1 = __builtin_bit_cast(bf16x8, *(const uint4*)bptr1);

                f32x4 acc0 = __builtin_amdgcn_mfma_f32_16x16x32_bf16(afrag[0][0], bf0, z4, 0, 0, 0);
                acc0 = __builtin_amdgcn_mfma_f32_16x16x32_bf16(afrag[0][1], bf1, acc0, 0, 0, 0);
                f32x4 acc1 = __builtin_amdgcn_mfma_f32_16x16x32_bf16(afrag[1][0], bf0, z4, 0, 0, 0);
                acc1 = __builtin_amdgcn_mfma_f32_16x16x32_bf16(afrag[1][1], bf1, acc1, 0, 0, 0);
                f32x4 acc2 = __builtin_amdgcn_mfma_f32_16x16x32_bf16(afrag[2][0], bf0, z4, 0, 0, 0);
                acc2 = __builtin_amdgcn_mfma_f32_16x16x32_bf16(afrag[2][1], bf1, acc2, 0, 0, 0);

                // deferred pow2 rescale: every 6 unmasked steps (overflow-safe;
                // per-step growth < 2^13, 6 steps < 2^78 << fp32/bf16 max 2^127).
                if (++cnt >= 6) {
                    float v00 = rdlanef(acc0[0], 0);
                    int k = (int)(__float_as_uint(v00) >> 23) - 127;
                    float r = __uint_as_float((unsigned int)(127 - k) << 23);
                    ls += k;
                    cnt = 0;
                    float4 ex0 = exf[sub][tt * 13 + q];
                    ex0.x *= r; ex0.y *= r; ex0.z *= r; ex0.w *= r;
                    *(uint2*)wp0 = make_uint2(pktrunc(acc0[0] * ex0.x, acc0[1] * ex0.y),
                                              pktrunc(acc0[2] * ex0.z, acc0[3] * ex0.w));
                    float4 ex1 = exf[sub][tt * 13 + 4 + q];
                    ex1.x *= r; ex1.y *= r; ex1.z *= r; ex1.w *= r;
                    *(uint2*)wp1 = make_uint2(pktrunc(acc1[0] * ex1.x, acc1[1] * ex1.y),
                                              pktrunc(acc1[2] * ex1.z, acc1[3] * ex1.w));
                    float4 ex2 = exf[sub][tt * 13 + 8 + q];
                    ex2.x *= r; ex2.y *= r; ex2.z *= r; ex2.w *= r;
                    *(uint2*)wp2 = make_uint2(pktrunc(acc2[0] * ex2.x, acc2[1] * ex2.y),
                                              pktrunc(acc2[2] * ex2.z, acc2[3] * ex2.w));
                } else {
                    float4 ex0 = exf[sub][tt * 13 + q];
                    *(uint2*)wp0 = make_uint2(pktrunc(acc0[0] * ex0.x, acc0[1] * ex0.y),
                                              pktrunc(acc0[2] * ex0.z, acc0[3] * ex0.w));
                    float4 ex1 = exf[sub][tt * 13 + 4 + q];
                    *(uint2*)wp1 = make_uint2(pktrunc(acc1[0] * ex1.x, acc1[1] * ex1.y),
                                              pktrunc(acc1[2] * ex1.z, acc1[3] * ex1.w));
                    float4 ex2 = exf[sub][tt * 13 + 8 + q];
                    *(uint2*)wp2 = make_uint2(pktrunc(acc2[0] * ex2.x, acc2[1] * ex2.y),
                                              pktrunc(acc2[2] * ex2.z, acc2[3] * ex2.w));
                }
            }
        }
    }

    __syncthreads();                         // both half-chains done; exf dead
    // stash sub-chain B scales + per-sub scores
    if (sub == 1 && wl < 3 && lane == 0) lsbB[wl] = ls;
    if (wl == 3) {
#pragma unroll
        for (int off = 32; off; off >>= 1) sc_acc += __shfl_xor(sc_acc, off);
        if (lane == 0) scpart[sub] = sc_acc;
    }
    // RB = row-major U_B staging (stride 64, cols 48-63 zeroed), overlaid on exf[1]
    bf16_t* RB = (bf16_t*)&exf[1][0];        // 6144 B <= 13312 B region
    __syncthreads();
    {   // zero RB (incl. pad cols used as zero K-tail by the fold MFMA)
        uint4* rp = (uint4*)RB;
        for (int i = tid; i < 384; i += 512) rp[i] = make_uint4(0, 0, 0, 0);
    }
    __syncthreads();
    // waves 4-6: reconcile U_B (per-wave pow2 scales -> lsbB[0]) into RB row-major
    if (sub == 1 && wl < 3 && lane < KK) {
        const int dl = ls - lsbB[0];
        unsigned int wd[8];
#pragma unroll
        for (int j = 0; j < 8; j++) {
            float f0 = ldexpf(bf2f(Ubuf[1][(16 * wl + 2 * j) * UST + lane]), dl);
            float f1 = ldexpf(bf2f(Ubuf[1][(16 * wl + 2 * j + 1) * UST + lane]), dl);
            wd[j] = bf16bits(f0) | (bf16bits(f1) << 16);
        }
        *(uint4*)(RB + lane * 64 + 16 * wl) = make_uint4(wd[0], wd[1], wd[2], wd[3]);
        *(uint4*)(RB + lane * 64 + 16 * wl + 8) = make_uint4(wd[4], wd[5], wd[6], wd[7]);
    }
    __syncthreads();
    // fold: waves 0-2 run ONE chain-like step with A-frags = U_B (rows 16mt+n,
    // k = 32ks+8q+j from RB row-major), B = U_A columns (bptr0/1), forced rescale.
    // Result overwrites Ubuf[0]; per-wave k folds into existing lsb mechanism.
    if (sub == 0 && wl < 3) {
        bf16x8 aB0, aB1, bf0, bf1;
        bf0 = __builtin_bit_cast(bf16x8, *(const uint4*)bptr0);
        bf1 = __builtin_bit_cast(bf16x8, *(const uint4*)bptr1);
        aB0 = __builtin_bit_cast(bf16x8, *(const uint4*)&RB[(16 * 0 + n) * 64 + 8 * q]);
        aB1 = __builtin_bit_cast(bf16x8, *(const uint4*)&RB[(16 * 0 + n) * 64 + 32 + 8 * q]);
        f32x4 acc0 = __builtin_amdgcn_mfma_f32_16x16x32_bf16(aB0, bf0, z4, 0, 0, 0);
        acc0 = __builtin_amdgcn_mfma_f32_16x16x32_bf16(aB1, bf1, acc0, 0, 0, 0);
        aB0 = __builtin_bit_cast(bf16x8, *(const uint4*)&RB[(16 * 1 + n) * 64 + 8 * q]);
        aB1 = __builtin_bit_cast(bf16x8, *(const uint4*)&RB[(16 * 1 + n) * 64 + 32 + 8 * q]);
        f32x4 acc1 = __builtin_amdgcn_mfma_f32_16x16x32_bf16(aB0, bf0, z4, 0, 0, 0);
        acc1 = __builtin_amdgcn_mfma_f32_16x16x32_bf16(aB1, bf1, acc1, 0, 0, 0);
        aB0 = __builtin_bit_cast(bf16x8, *(const uint4*)&RB[(16 * 2 + n) * 64 + 8 * q]);
        aB1 = __builtin_bit_cast(bf16x8, *(const uint4*)&RB[(16 * 2 + n) * 64 + 32 + 8 * q]);
        f32x4 acc2 = __builtin_amdgcn_mfma_f32_16x16x32_bf16(aB0, bf0, z4, 0, 0, 0);
        acc2 = __builtin_amdgcn_mfma_f32_16x16x32_bf16(aB1, bf1, acc2, 0, 0, 0);

        float v00 = rdlanef(acc0[0], 0);
        int k = (int)(__float_as_uint(v00) >> 23) - 127;
        float r = __uint_as_float((unsigned int)(127 - k) << 23);
        ls += k;
        *(uint2*)wp0 = make_uint2(pktrunc(acc0[0] * r, acc0[1] * r),
                                  pktrunc(acc0[2] * r, acc0[3] * r));
        *(uint2*)wp1 = make_uint2(pktrunc(acc1[0] * r, acc1[1] * r),
                                  pktrunc(acc1[2] * r, acc1[3] * r));
        *(uint2*)wp2 = make_uint2(pktrunc(acc2[0] * r, acc2[1] * r),
                                  pktrunc(acc2[2] * r, acc2[3] * r));
    }
    if (sub == 0 && wl < 3 && lane == 0) lsbA[wl] = ls;
    __syncthreads();
    // epilogue: waves 0-2 reconcile + write compact 48x48 bf16 block
    if (sub == 0 && wl < 3 && lane < KK) {
        const int dl = ls - lsbA[0];
        bf16_t* Uo = ws_u + (size_t)(b * nseg + s) * SEGELEMS;
        unsigned int wd[8];
#pragma unroll
        for (int j = 0; j < 8; j++) {
            float f0 = ldexpf(bf2f(Ubuf[0][(16 * wl + 2 * j) * UST + lane]), dl);
            float f1 = ldexpf(bf2f(Ubuf[0][(16 * wl + 2 * j + 1) * UST + lane]), dl);
            wd[j] = bf16bits(f0) | (bf16bits(f1) << 16);
        }
        *(uint4*)(Uo + (size_t)lane * 48 + 16 * wl) = make_uint4(wd[0], wd[1], wd[2], wd[3]);
        *(uint4*)(Uo + (size_t)lane * 48 + 16 * wl + 8) = make_uint4(wd[4], wd[5], wd[6], wd[7]);
    }
    if (tid == 0) {
        ws_ls[b * nseg + s] = lsbA[0] + lsbB[0];
        ws_target[b * nseg + s] = scpart[0] + scpart[1];
    }
}

// 48x48 product: D = A (global row-major 48x48) x W (LDS col-major stride PST), in place.
// Returns pow2 scale exponent removed. No barriers inside (single-wave safe).
__device__ __forceinline__ int chain_product(const bf16_t* __restrict__ A, bf16_t* Ub, int lane) {
    const int half = lane >> 5;
    const int l31 = lane & 31;
    f32x16 z16;
#pragma unroll
    for (int r = 0; r < 16; r++) z16[r] = 0.0f;

    bf16x8 af[2][3];
#pragma unroll
    for (int mt = 0; mt < 2; mt++) {
        int m = l31 + 32 * mt;
#pragma unroll
        for (int ks = 0; ks < 3; ks++) {
            if (m < KK)
                af[mt][ks] = __builtin_bit_cast(bf16x8, *(const uint4*)&A[(size_t)m * 48 + 16 * ks + 8 * half]);
            else
                af[mt][ks] = __builtin_bit_cast(bf16x8, make_uint4(0, 0, 0, 0));
        }
    }
    bf16x8 bg[3][2];
#pragma unroll
    for (int ks = 0; ks < 3; ks++)
#pragma unroll
        for (int nt = 0; nt < 2; nt++)
            bg[ks][nt] = __builtin_bit_cast(bf16x8, *(const uint4*)&Ub[(l31 + 32 * nt) * PST + 16 * ks + 8 * half]);

    f32x16 acc[4];
#pragma unroll
    for (int mt = 0; mt < 2; mt++)
#pragma unroll
        for (int nt = 0; nt < 2; nt++) {
            f32x16 a0 = __builtin_amdgcn_mfma_f32_32x32x16_bf16(af[mt][0], bg[0][nt], z16, 0, 0, 0);
            a0 = __builtin_amdgcn_mfma_f32_32x32x16_bf16(af[mt][1], bg[1][nt], a0, 0, 0, 0);
            acc[mt * 2 + nt] = __builtin_amdgcn_mfma_f32_32x32x16_bf16(af[mt][2], bg[2][nt], a0, 0, 0, 0);
        }

    float v00 = rdlanef(acc[0][0], 0);
    int k = (int)(__float_as_uint(v00) >> 23) - 127;
    float r = __uint_as_float((unsigned int)(127 - k) << 23);

#pragma unroll
    for (int mt = 0; mt < 2; mt++)
#pragma unroll
        for (int nt = 0; nt < 2; nt++) {
            int c = l31 + 32 * nt;
#pragma unroll
            for (int g = 0; g < 4; g++) {
                int a0 = 32 * mt + 8 * g + 4 * half;
                if (a0 < KK) {
                    const f32x16& Aq = acc[mt * 2 + nt];
                    unsigned int u0 = bf16bits(Aq[4 * g + 0] * r) | (bf16bits(Aq[4 * g + 1] * r) << 16);
                    unsigned int u1 = bf16bits(Aq[4 * g + 2] * r) | (bf16bits(Aq[4 * g + 3] * r) << 16);
                    *(uint2*)&Ub[c * PST + a0] = make_uint2(u0, u1);
                }
            }
        }
    return k;
}

// Variant: A read from LDS col-major slot (A[m][k] = As[k*PST + m]).
__device__ __forceinline__ int chain_product_ldsA(const bf16_t* As, bf16_t* Ub, int lane) {
    const int half = lane >> 5;
    const int l31 = lane & 31;
    f32x16 z16;
#pragma unroll
    for (int r = 0; r < 16; r++) z16[r] = 0.0f;

    bf16x8 af[2][3];
#pragma unroll
    for (int mt = 0; mt < 2; mt++) {
        int m = l31 + 32 * mt;
#pragma unroll
        for (int ks = 0; ks < 3; ks++) {
            bf16x8 f;
#pragma unroll
            for (int j = 0; j < 8; j++) {
                int k = 16 * ks + 8 * half + j;
                f[j] = (m < KK) ? As[k * PST + m] : (bf16_t)0.0f;
            }
            af[mt][ks] = f;
        }
    }
    bf16x8 bg[3][2];
#pragma unroll
    for (int ks = 0; ks < 3; ks++)
#pragma unroll
        for (int nt = 0; nt < 2; nt++)
            bg[ks][nt] = __builtin_bit_cast(bf16x8, *(const uint4*)&Ub[(l31 + 32 * nt) * PST + 16 * ks + 8 * half]);

    f32x16 acc[4];
#pragma unroll
    for (int mt = 0; mt < 2; mt++)
#pragma unroll
        for (int nt = 0; nt < 2; nt++) {
            f32x16 a0 = __builtin_amdgcn_mfma_f32_32x32x16_bf16(af[mt][0], bg[0][nt], z16, 0, 0, 0);
            a0 = __builtin_amdgcn_mfma_f32_32x32x16_bf16(af[mt][1], bg[1][nt], a0, 0, 0, 0);
            acc[mt * 2 + nt] = __builtin_amdgcn_mfma_f32_32x32x16_bf16(af[mt][2], bg[2][nt], a0, 0, 0, 0);
        }

    float v00 = rdlanef(acc[0][0], 0);
    int k = (int)(__float_as_uint(v00) >> 23) - 127;
    float r = __uint_as_float((unsigned int)(127 - k) << 23);

#pragma unroll
    for (int mt = 0; mt < 2; mt++)
#pragma unroll
        for (int nt = 0; nt < 2; nt++) {
            int c = l31 + 32 * nt;
#pragma unroll
            for (int g = 0; g < 4; g++) {
                int a0 = 32 * mt + 8 * g + 4 * half;
                if (a0 < KK) {
                    const f32x16& Aq = acc[mt * 2 + nt];
                    unsigned int u0 = bf16bits(Aq[4 * g + 0] * r) | (bf16bits(Aq[4 * g + 1] * r) << 16);
                    unsigned int u1 = bf16bits(Aq[4 * g + 2] * r) | (bf16bits(Aq[4 * g + 3] * r) << 16);
                    *(uint2*)&Ub[c * PST + a0] = make_uint2(u0, u1);
                }
            }
        }
    return k;
}

// ============ fold8: parallel tree fold of 8 consecutive segments per block ============
__global__ __launch_bounds__(256) void fold8_kernel(
    bf16_t* __restrict__ ws_u, int* __restrict__ ws_ls, int nseg) {
    const int s8 = blockIdx.x, b = blockIdx.y;
    const int tid = threadIdx.x;
    const int w = tid >> 6, lane = tid & 63;
    const int base = b * nseg + s8 * 8;

    __shared__ __align__(16) bf16_t Ws[4][64 * PST];   // 4 x 7 KB
    __shared__ int lsp[8];

    {   // pair product: Ws[w] = U_{2w+1} * U_{2w}  (later segment on the left)
        const bf16_t* sE = ws_u + (size_t)(base + 2 * w) * SEGELEMS;
        for (int k = 0; k < KK; k++)
            Ws[w][lane * PST + k] = (lane < KK) ? sE[(size_t)k * 48 + lane] : (bf16_t)0.0f;
        int lsk = ws_ls[base + 2 * w] + ws_ls[base + 2 * w + 1];
        lsk += chain_product(ws_u + (size_t)(base + 2 * w + 1) * SEGELEMS, Ws[w], lane);
        if (lane == 0) lsp[w] = lsk;
    }
    __syncthreads();
    int k1 = 0;
    if (w == 0) k1 = chain_product_ldsA(Ws[1], Ws[0], lane);        // Ws0 = W1*W0
    if (w == 2) {                                                    // Ws2 = W3*W2
        int k2 = chain_product_ldsA(Ws[3], Ws[2], lane);
        if (lane == 0) lsp[5] = k2;
    }
    __syncthreads();
    if (w == 0) {
        int k3 = chain_product_ldsA(Ws[2], Ws[0], lane);             // Ws0 = (W3W2)(W1W0)
        // write folded 48x48 back into slot 'base' (row-major, stride 48)
        if (lane < KK) {
            bf16_t* Uo = ws_u + (size_t)base * SEGELEMS;
            unsigned int wd[24];
#pragma unroll
            for (int j = 0; j < 24; j++) {
                unsigned int lo = (unsigned int)__builtin_bit_cast(unsigned short, Ws[0][(2 * j) * PST + lane]);
                unsigned int hi = (unsigned int)__builtin_bit_cast(unsigned short, Ws[0][(2 * j + 1) * PST + lane]);
                wd[j] = lo | (hi << 16);
            }
#pragma unroll
            for (int g = 0; g < 6; g++)
                *(uint4*)(Uo + (size_t)lane * 48 + 8 * g) =
                    make_uint4(wd[4 * g], wd[4 * g + 1], wd[4 * g + 2], wd[4 * g + 3]);
        }
        if (lane == 0)
            ws_ls[base] = lsp[0] + lsp[1] + lsp[2] + lsp[3] + k1 + lsp[5] + k3;
    }
}

// ============ final: fold the npart partials (tree) + q0 + output ============
__global__ __launch_bounds__(256) void final_kernel(
    const float* __restrict__ y_pred, const bf16_t* __restrict__ ws_u,
    const int* __restrict__ ws_ls, const float* __restrict__ ws_target,
    float* __restrict__ out, int nseg) {
    const int b = blockIdx.x;
    const int tid = threadIdx.x;
    const int w = tid >> 6, lane = tid & 63;
    const int npart = nseg / 8;            // 2 or 4

    __shared__ __align__(16) bf16_t Ws[4][64 * PST];
    __shared__ int lsp[8];
    if (tid < 8) lsp[tid] = 0;
    __syncthreads();

    if (2 * w < npart) {                   // pair product on partials 2w, 2w+1
        const int slotE = b * nseg + 16 * w;
        const int slotL = slotE + 8;
        const bf16_t* sE = ws_u + (size_t)slotE * SEGELEMS;
        for (int k = 0; k < KK; k++)
            Ws[w][lane * PST + k] = (lane < KK) ? sE[(size_t)k * 48 + lane] : (bf16_t)0.0f;
        int lsk = ws_ls[slotE] + ws_ls[slotL];
        lsk += chain_product(ws_u + (size_t)slotL * SEGELEMS, Ws[w], lane);
        if (lane == 0) lsp[w] = lsk;
    }
    __syncthreads();
    int k1 = 0;
    if (npart >= 4 && w == 0) k1 = chain_product_ldsA(Ws[1], Ws[0], lane);
    if (npart == 8 && w == 2) {
        int k2 = chain_product_ldsA(Ws[3], Ws[2], lane);
        if (lane == 0) lsp[5] = k2;
    }
    __syncthreads();

    if (w == 0) {
        int k3 = 0;
        if (npart == 8) k3 = chain_product_ldsA(Ws[2], Ws[0], lane);
        float L = (float)(lsp[0] + lsp[1] + lsp[2] + lsp[3] + k1 + lsp[5] + k3);

        // q0 from t=0 row
        float x0 = (lane < KK) ? y_pred[(size_t)b * TT * KK + lane] : 0.0f;
        bool ok0 = (lane >= KK) || (x0 > -1e6f);
        bool m0 = (__ballot(ok0) == ~0ull);
        float xeff = (lane < KK) ? (m0 ? x0 : 0.0f) : 0.0f;
        float c0 = rdlanef(xeff, 0);
        float q0 = (lane < KK) ? fexp(xeff - c0) : 0.0f;

        float p = 0.0f;
        if (lane < KK) {
            for (int c = 0; c < KK; c++) {
                float qc = rdlanef(q0, c);
                p = fmaf(bf2f(Ws[0][c * PST + lane]), qc, p);
            }
        }
#pragma unroll
        for (int off = 32; off; off >>= 1) p += __shfl_xor(p, off);

        // target = sum of per-block partials
        float tg = (lane < nseg) ? ws_target[b * nseg + lane] : 0.0f;
#pragma unroll
        for (int off = 32; off; off >>= 1) tg += __shfl_xor(tg, off);

        if (lane == 0) {
            out[b] = c0 + 0.6931471805599453f * (L + flog2(p)) - tg;
        }
    }
}

extern "C" void kernel_launch(void* const* d_in, const int* in_sizes, int n_in,
                              void* d_out, int out_size, void* d_ws, size_t ws_size,
                              hipStream_t stream) {
    const float* y_true = (const float*)d_in[0];
    const float* y_pred = (const float*)d_in[1];
    const float* trans = (const float*)d_in[2];
    float* out = (float*)d_out;

    // adaptive segment count (never overrun d_ws). Tiers: 16 / 32 only — the
    // in-block split needs seglen >= 128 (nseg <= 32); evidence (r6): ws < 9.5 MB
    // so 32 won't fire on this harness, but keep the tier for larger workspaces.
    int nseg = 16;
    if (ws_size >= (size_t)WS_U_OFF + (size_t)BB * 32 * SEGBYTES) nseg = 32;

    float* ws_target = (float*)d_ws;                          // BB*nseg floats (<=16 KB)
    int* ws_ls = (int*)((char*)d_ws + WS_LS_OFF);             // BB*nseg ints  (<=16 KB)
    bf16_t* ws_u = (bf16_t*)((char*)d_ws + WS_U_OFF);

    fused_kernel<<<dim3(nseg, BB), 512, 0, stream>>>(
        y_true, y_pred, trans, ws_target, ws_ls, ws_u, nseg);
    fold8_kernel<<<dim3(nseg / 8, BB), 256, 0, stream>>>(ws_u, ws_ls, nseg);
    final_kernel<<<BB, 256, 0, stream>>>(y_pred, ws_u, ws_ls, ws_target, out, nseg);
}

// Round 8
// 258.453 us; speedup vs baseline: 1.0297x; 1.0297x over previous
//
#include <hip/hip_runtime.h>

#define BB 64
#define TT 4096
#define KK 48
#define UST 56              // Ubuf col stride (bf16): 112 B. MUST be mult of 8 elems
                            // (16 B): r5's UST=58 misaligned ds_read_b128 -> 3.6x slower.
#define PST 56              // phase LDS col stride (bf16)
#define WS_LS_OFF 16384
#define WS_U_OFF 32768
#define SEGBYTES 4608       // compact: 48 rows x 48 col-stride x bf16
#define SEGELEMS 2304

typedef __bf16 bf16_t;
typedef bf16_t bf16x8 __attribute__((ext_vector_type(8)));
typedef float f32x4 __attribute__((ext_vector_type(4)));
typedef float f32x16 __attribute__((ext_vector_type(16)));

__device__ __forceinline__ float fexp(float x) {   // natural exp
    return __builtin_amdgcn_exp2f(x * 1.4426950408889634f);
}
__device__ __forceinline__ float flog2(float x) { return __builtin_amdgcn_logf(x); }
__device__ __forceinline__ float rdlanef(float v, int l) {
    return __int_as_float(__builtin_amdgcn_readlane(__float_as_int(v), l));
}
__device__ __forceinline__ unsigned int bf16bits(float f) {
    return (unsigned int)__builtin_bit_cast(unsigned short, (bf16_t)f);
}
__device__ __forceinline__ float bf2f(bf16_t h) {
    return __uint_as_float(((unsigned int)__builtin_bit_cast(unsigned short, h)) << 16);
}
// pack two fp32 -> bf16x2 by truncation (1 v_perm_b32); lo in low half
__device__ __forceinline__ unsigned int pktrunc(float lo, float hi) {
    return __builtin_amdgcn_perm(__float_as_uint(hi), __float_as_uint(lo), 0x07060302u);
}

// ============ fused: 8-wave block = 2 parallel half-chains + in-block compose ====
// r8 = r7 structure with the launch bound FIXED: (512,8) forced the compiler's
// 256/w budget to 32 VGPR -> chain spilled to scratch (r7: WRITE_SIZE 18.7->194 MB,
// fused 177 us, HBM 1.7 TB/s of pure spill traffic). (512,4) gives budget 64;
// chain naturally allocs ~48 (r3/r6 verified) -> no spill, and the HW still
// schedules 4 blocks/CU = 32 waves/CU because actual VGPR<=64 (m69) and LDS
// 37.9 KB -> 4 blocks. Structure: waves 0-3 = sub-chain A (chunks [0,nch/2),
// exf[0]/Ubuf[0]); waves 4-7 = sub-chain B; then U_seg = U_B x U_A composed
// in-block via one extra MFMA step (A-frags = U_B from row-major RB overlay).
__global__ __launch_bounds__(512, 4) void fused_kernel(
    const float* __restrict__ y_true, const float* __restrict__ y_pred,
    const float* __restrict__ trans, float* __restrict__ ws_target,
    int* __restrict__ ws_ls, bf16_t* __restrict__ ws_u, int nseg) {
    const int s = blockIdx.x, b = blockIdx.y;
    const int seglen = TT / nseg;
    const int nch_sub = seglen / 128;       // chunks per sub-chain (>=1 for nseg<=32)
    const int tid = threadIdx.x;
    const int w = tid >> 6;                 // 0..7
    const int sub = w >> 2;                 // sub-chain id 0/1
    const int wl = w & 3;                   // role within sub-chain: 0-2 chain, 3 producer
    const int lane = tid & 63;
    const int q = lane >> 4;
    const int n = lane & 15;
    const int ncol = 16 * wl + n;

    __shared__ __align__(16) float4 exf[2][64 * 13];          // fp32 ex per sub-chain
    __shared__ __align__(16) bf16_t Ubuf[2][48 * UST + 16];   // U state per sub-chain
    __shared__ unsigned long long pb[2];
    __shared__ int lsbA[4], lsbB[4];
    __shared__ float scpart[2];

    // A fragments (chain waves of both subs): E^T zero-padded in K.
    bf16x8 afrag[3][2];
    if (wl < 3) {
#pragma unroll
        for (int mt = 0; mt < 3; mt++) {
#pragma unroll
            for (int ks = 0; ks < 2; ks++) {
                bf16x8 f;
#pragma unroll
                for (int j = 0; j < 8; j++) {
                    int k = 32 * ks + 8 * q + j;
                    float v = (k < KK) ? fexp(trans[k * KK + 16 * mt + n]) : 0.0f;
                    f[j] = (bf16_t)v;
                }
                afrag[mt][ks] = f;
            }
        }
    }

    {   // zero both Ubufs then identity diags
        uint4* p = (uint4*)&Ubuf[0][0];
        const int nq = 2 * (48 * UST + 16) / 8;
        for (int i = tid; i < nq; i += 512) p[i] = make_uint4(0, 0, 0, 0);
    }
    __syncthreads();
    if (tid < KK) {
        Ubuf[0][tid * UST + tid] = (bf16_t)1.0f;
        Ubuf[1][tid * UST + tid] = (bf16_t)1.0f;
    }

    const bf16_t* bptr0 = &Ubuf[sub][ncol * UST + 8 * q];
    const bf16_t* bptr1 = &Ubuf[sub][ncol * UST + 32 + 8 * q];
    bf16_t* wp0 = &Ubuf[sub][ncol * UST + 0 + 4 * q];
    bf16_t* wp1 = &Ubuf[sub][ncol * UST + 16 + 4 * q];
    bf16_t* wp2 = &Ubuf[sub][ncol * UST + 32 + 4 * q];

    f32x4 z4 = {0.0f, 0.0f, 0.0f, 0.0f};
    int ls = 0;
    int cnt = 0;          // unmasked steps since last rescale (wave-uniform)
    float sc_acc = 0.0f;  // producers: scores accumulator

    for (int ch = 0; ch < nch_sub; ch++) {
        __syncthreads();                     // previous exf fully consumed
        if (wl == 3) {
            // ---- producer + scores: lane = local timestep ----
            const int gch = sub * nch_sub + ch;
            const int t0c = s * seglen + gch * 64;
            const size_t rowbase = ((size_t)b * TT + t0c + lane) * KK;
            const float4* yp4 = (const float4*)(y_pred + rowbase);
            const float4* yt4 = (const float4*)(y_true + rowbase);
            float dot = 0.0f, labf = 0.0f, pmin = 1e30f;
            float4* exrow = &exf[sub][lane * 13];
#pragma unroll 4
            for (int g = 0; g < 12; g++) {
                float4 p = yp4[g];
                float4 a = yt4[g];
                dot = fmaf(a.x, p.x, fmaf(a.y, p.y, fmaf(a.z, p.z, fmaf(a.w, p.w, dot))));
                float e0 = (float)(4 * g);
                labf = fmaf(a.x, e0, fmaf(a.y, e0 + 1.0f, fmaf(a.z, e0 + 2.0f, fmaf(a.w, e0 + 3.0f, labf))));
                pmin = fminf(pmin, fminf(fminf(p.x, p.y), fminf(p.z, p.w)));
                exrow[g] = make_float4(fexp(p.x), fexp(p.y), fexp(p.z), fexp(p.w));
            }
            bool mt_ok = pmin > -1e6f;
            unsigned long long bal = __ballot(mt_ok);
            if (lane == 0) pb[sub] = bal;

            // boundary row t0c+64 (label+mask), lanes 0..11 partials
            float labB = 0.0f, pmB = 1e30f;
            const bool hasB = (t0c + 64 < TT);
            if (hasB && lane < 12) {
                const size_t bdbase = ((size_t)b * TT + t0c + 64) * KK;
                float4 a = ((const float4*)(y_true + bdbase))[lane];
                float4 p = ((const float4*)(y_pred + bdbase))[lane];
                float e0 = (float)(4 * lane);
                labB = fmaf(a.x, e0, fmaf(a.y, e0 + 1.0f, fmaf(a.z, e0 + 2.0f, a.w * (e0 + 3.0f))));
                pmB = fminf(fminf(p.x, p.y), fminf(p.z, p.w));
            }
#pragma unroll
            for (int off = 1; off < 16; off <<= 1) {
                labB += __shfl_xor(labB, off);
                pmB = fminf(pmB, __shfl_xor(pmB, off));
            }
            int labB_i = (int)(rdlanef(labB, 0) + 0.5f);
            float mB = (hasB && rdlanef(pmB, 0) > -1e6f) ? 1.0f : 0.0f;

            int labt = (int)(labf + 0.5f);
            float mft = mt_ok ? 1.0f : 0.0f;
            int lnx = __shfl(labt, (lane + 1) & 63);
            float mnx = __shfl(mft, (lane + 1) & 63);
            if (lane == 63) { lnx = labB_i; mnx = mB; }
            sc_acc += mft * dot + mft * mnx * trans[labt * KK + lnx];
        }
        __syncthreads();
        if (wl < 3) {
            const unsigned long long mk = pb[sub];
            const int tt0 = (s == 0 && sub == 0 && ch == 0) ? 1 : 0;
            for (int tt = tt0; tt < 64; tt++) {
                if (!((mk >> tt) & 1ull)) continue;

                bf16x8 bf0 = __builtin_bit_cast(bf16x8, *(const uint4*)bptr0);
                bf16x8 bf1 = __builtin_bit_cast(bf16x8, *(const uint4*)bptr1);

                f32x4 acc0 = __builtin_amdgcn_mfma_f32_16x16x32_bf16(afrag[0][0], bf0, z4, 0, 0, 0);
                acc0 = __builtin_amdgcn_mfma_f32_16x16x32_bf16(afrag[0][1], bf1, acc0, 0, 0, 0);
                f32x4 acc1 = __builtin_amdgcn_mfma_f32_16x16x32_bf16(afrag[1][0], bf0, z4, 0, 0, 0);
                acc1 = __builtin_amdgcn_mfma_f32_16x16x32_bf16(afrag[1][1], bf1, acc1, 0, 0, 0);
                f32x4 acc2 = __builtin_amdgcn_mfma_f32_16x16x32_bf16(afrag[2][0], bf0, z4, 0, 0, 0);
                acc2 = __builtin_amdgcn_mfma_f32_16x16x32_bf16(afrag[2][1], bf1, acc2, 0, 0, 0);

                // deferred pow2 rescale: every 6 unmasked steps (overflow-safe;
                // per-step growth < 2^13, 6 steps < 2^78 << fp32/bf16 max 2^127).
                if (++cnt >= 6) {
                    float v00 = rdlanef(acc0[0], 0);
                    int k = (int)(__float_as_uint(v00) >> 23) - 127;
                    float r = __uint_as_float((unsigned int)(127 - k) << 23);
                    ls += k;
                    cnt = 0;
                    float4 ex0 = exf[sub][tt * 13 + q];
                    ex0.x *= r; ex0.y *= r; ex0.z *= r; ex0.w *= r;
                    *(uint2*)wp0 = make_uint2(pktrunc(acc0[0] * ex0.x, acc0[1] * ex0.y),
                                              pktrunc(acc0[2] * ex0.z, acc0[3] * ex0.w));
                    float4 ex1 = exf[sub][tt * 13 + 4 + q];
                    ex1.x *= r; ex1.y *= r; ex1.z *= r; ex1.w *= r;
                    *(uint2*)wp1 = make_uint2(pktrunc(acc1[0] * ex1.x, acc1[1] * ex1.y),
                                              pktrunc(acc1[2] * ex1.z, acc1[3] * ex1.w));
                    float4 ex2 = exf[sub][tt * 13 + 8 + q];
                    ex2.x *= r; ex2.y *= r; ex2.z *= r; ex2.w *= r;
                    *(uint2*)wp2 = make_uint2(pktrunc(acc2[0] * ex2.x, acc2[1] * ex2.y),
                                              pktrunc(acc2[2] * ex2.z, acc2[3] * ex2.w));
                } else {
                    float4 ex0 = exf[sub][tt * 13 + q];
                    *(uint2*)wp0 = make_uint2(pktrunc(acc0[0] * ex0.x, acc0[1] * ex0.y),
                                              pktrunc(acc0[2] * ex0.z, acc0[3] * ex0.w));
                    float4 ex1 = exf[sub][tt * 13 + 4 + q];
                    *(uint2*)wp1 = make_uint2(pktrunc(acc1[0] * ex1.x, acc1[1] * ex1.y),
                                              pktrunc(acc1[2] * ex1.z, acc1[3] * ex1.w));
                    float4 ex2 = exf[sub][tt * 13 + 8 + q];
                    *(uint2*)wp2 = make_uint2(pktrunc(acc2[0] * ex2.x, acc2[1] * ex2.y),
                                              pktrunc(acc2[2] * ex2.z, acc2[3] * ex2.w));
                }
            }
        }
    }

    __syncthreads();                         // both half-chains done; exf dead
    // stash sub-chain B scales + per-sub scores
    if (sub == 1 && wl < 3 && lane == 0) lsbB[wl] = ls;
    if (wl == 3) {
#pragma unroll
        for (int off = 32; off; off >>= 1) sc_acc += __shfl_xor(sc_acc, off);
        if (lane == 0) scpart[sub] = sc_acc;
    }
    // RB = row-major U_B staging (stride 64, cols 48-63 zeroed), overlaid on exf[1]
    bf16_t* RB = (bf16_t*)&exf[1][0];        // 6144 B <= 13312 B region
    __syncthreads();
    {   // zero RB (incl. pad cols used as zero K-tail by the fold MFMA)
        uint4* rp = (uint4*)RB;
        for (int i = tid; i < 384; i += 512) rp[i] = make_uint4(0, 0, 0, 0);
    }
    __syncthreads();
    // waves 4-6: reconcile U_B (per-wave pow2 scales -> lsbB[0]) into RB row-major
    if (sub == 1 && wl < 3 && lane < KK) {
        const int dl = ls - lsbB[0];
        unsigned int wd[8];
#pragma unroll
        for (int j = 0; j < 8; j++) {
            float f0 = ldexpf(bf2f(Ubuf[1][(16 * wl + 2 * j) * UST + lane]), dl);
            float f1 = ldexpf(bf2f(Ubuf[1][(16 * wl + 2 * j + 1) * UST + lane]), dl);
            wd[j] = bf16bits(f0) | (bf16bits(f1) << 16);
        }
        *(uint4*)(RB + lane * 64 + 16 * wl) = make_uint4(wd[0], wd[1], wd[2], wd[3]);
        *(uint4*)(RB + lane * 64 + 16 * wl + 8) = make_uint4(wd[4], wd[5], wd[6], wd[7]);
    }
    __syncthreads();
    // fold: waves 0-2 run ONE chain-like step with A-frags = U_B (rows 16mt+n,
    // k = 32ks+8q+j from RB row-major), B = U_A columns (bptr0/1), forced rescale.
    // Result overwrites Ubuf[0]; per-wave k folds into existing lsb mechanism.
    if (sub == 0 && wl < 3) {
        bf16x8 aB0, aB1, bf0, bf1;
        bf0 = __builtin_bit_cast(bf16x8, *(const uint4*)bptr0);
        bf1 = __builtin_bit_cast(bf16x8, *(const uint4*)bptr1);
        aB0 = __builtin_bit_cast(bf16x8, *(const uint4*)&RB[(16 * 0 + n) * 64 + 8 * q]);
        aB1 = __builtin_bit_cast(bf16x8, *(const uint4*)&RB[(16 * 0 + n) * 64 + 32 + 8 * q]);
        f32x4 acc0 = __builtin_amdgcn_mfma_f32_16x16x32_bf16(aB0, bf0, z4, 0, 0, 0);
        acc0 = __builtin_amdgcn_mfma_f32_16x16x32_bf16(aB1, bf1, acc0, 0, 0, 0);
        aB0 = __builtin_bit_cast(bf16x8, *(const uint4*)&RB[(16 * 1 + n) * 64 + 8 * q]);
        aB1 = __builtin_bit_cast(bf16x8, *(const uint4*)&RB[(16 * 1 + n) * 64 + 32 + 8 * q]);
        f32x4 acc1 = __builtin_amdgcn_mfma_f32_16x16x32_bf16(aB0, bf0, z4, 0, 0, 0);
        acc1 = __builtin_amdgcn_mfma_f32_16x16x32_bf16(aB1, bf1, acc1, 0, 0, 0);
        aB0 = __builtin_bit_cast(bf16x8, *(const uint4*)&RB[(16 * 2 + n) * 64 + 8 * q]);
        aB1 = __builtin_bit_cast(bf16x8, *(const uint4*)&RB[(16 * 2 + n) * 64 + 32 + 8 * q]);
        f32x4 acc2 = __builtin_amdgcn_mfma_f32_16x16x32_bf16(aB0, bf0, z4, 0, 0, 0);
        acc2 = __builtin_amdgcn_mfma_f32_16x16x32_bf16(aB1, bf1, acc2, 0, 0, 0);

        float v00 = rdlanef(acc0[0], 0);
        int k = (int)(__float_as_uint(v00) >> 23) - 127;
        float r = __uint_as_float((unsigned int)(127 - k) << 23);
        ls += k;
        *(uint2*)wp0 = make_uint2(pktrunc(acc0[0] * r, acc0[1] * r),
                                  pktrunc(acc0[2] * r, acc0[3] * r));
        *(uint2*)wp1 = make_uint2(pktrunc(acc1[0] * r, acc1[1] * r),
                                  pktrunc(acc1[2] * r, acc1[3] * r));
        *(uint2*)wp2 = make_uint2(pktrunc(acc2[0] * r, acc2[1] * r),
                                  pktrunc(acc2[2] * r, acc2[3] * r));
    }
    if (sub == 0 && wl < 3 && lane == 0) lsbA[wl] = ls;
    __syncthreads();
    // epilogue: waves 0-2 reconcile + write compact 48x48 bf16 block
    if (sub == 0 && wl < 3 && lane < KK) {
        const int dl = ls - lsbA[0];
        bf16_t* Uo = ws_u + (size_t)(b * nseg + s) * SEGELEMS;
        unsigned int wd[8];
#pragma unroll
        for (int j = 0; j < 8; j++) {
            float f0 = ldexpf(bf2f(Ubuf[0][(16 * wl + 2 * j) * UST + lane]), dl);
            float f1 = ldexpf(bf2f(Ubuf[0][(16 * wl + 2 * j + 1) * UST + lane]), dl);
            wd[j] = bf16bits(f0) | (bf16bits(f1) << 16);
        }
        *(uint4*)(Uo + (size_t)lane * 48 + 16 * wl) = make_uint4(wd[0], wd[1], wd[2], wd[3]);
        *(uint4*)(Uo + (size_t)lane * 48 + 16 * wl + 8) = make_uint4(wd[4], wd[5], wd[6], wd[7]);
    }
    if (tid == 0) {
        ws_ls[b * nseg + s] = lsbA[0] + lsbB[0];
        ws_target[b * nseg + s] = scpart[0] + scpart[1];
    }
}

// 48x48 product: D = A (global row-major 48x48) x W (LDS col-major stride PST), in place.
// Returns pow2 scale exponent removed. No barriers inside (single-wave safe).
__device__ __forceinline__ int chain_product(const bf16_t* __restrict__ A, bf16_t* Ub, int lane) {
    const int half = lane >> 5;
    const int l31 = lane & 31;
    f32x16 z16;
#pragma unroll
    for (int r = 0; r < 16; r++) z16[r] = 0.0f;

    bf16x8 af[2][3];
#pragma unroll
    for (int mt = 0; mt < 2; mt++) {
        int m = l31 + 32 * mt;
#pragma unroll
        for (int ks = 0; ks < 3; ks++) {
            if (m < KK)
                af[mt][ks] = __builtin_bit_cast(bf16x8, *(const uint4*)&A[(size_t)m * 48 + 16 * ks + 8 * half]);
            else
                af[mt][ks] = __builtin_bit_cast(bf16x8, make_uint4(0, 0, 0, 0));
        }
    }
    bf16x8 bg[3][2];
#pragma unroll
    for (int ks = 0; ks < 3; ks++)
#pragma unroll
        for (int nt = 0; nt < 2; nt++)
            bg[ks][nt] = __builtin_bit_cast(bf16x8, *(const uint4*)&Ub[(l31 + 32 * nt) * PST + 16 * ks + 8 * half]);

    f32x16 acc[4];
#pragma unroll
    for (int mt = 0; mt < 2; mt++)
#pragma unroll
        for (int nt = 0; nt < 2; nt++) {
            f32x16 a0 = __builtin_amdgcn_mfma_f32_32x32x16_bf16(af[mt][0], bg[0][nt], z16, 0, 0, 0);
            a0 = __builtin_amdgcn_mfma_f32_32x32x16_bf16(af[mt][1], bg[1][nt], a0, 0, 0, 0);
            acc[mt * 2 + nt] = __builtin_amdgcn_mfma_f32_32x32x16_bf16(af[mt][2], bg[2][nt], a0, 0, 0, 0);
        }

    float v00 = rdlanef(acc[0][0], 0);
    int k = (int)(__float_as_uint(v00) >> 23) - 127;
    float r = __uint_as_float((unsigned int)(127 - k) << 23);

#pragma unroll
    for (int mt = 0; mt < 2; mt++)
#pragma unroll
        for (int nt = 0; nt < 2; nt++) {
            int c = l31 + 32 * nt;
#pragma unroll
            for (int g = 0; g < 4; g++) {
                int a0 = 32 * mt + 8 * g + 4 * half;
                if (a0 < KK) {
                    const f32x16& Aq = acc[mt * 2 + nt];
                    unsigned int u0 = bf16bits(Aq[4 * g + 0] * r) | (bf16bits(Aq[4 * g + 1] * r) << 16);
                    unsigned int u1 = bf16bits(Aq[4 * g + 2] * r) | (bf16bits(Aq[4 * g + 3] * r) << 16);
                    *(uint2*)&Ub[c * PST + a0] = make_uint2(u0, u1);
                }
            }
        }
    return k;
}

// Variant: A read from LDS col-major slot (A[m][k] = As[k*PST + m]).
__device__ __forceinline__ int chain_product_ldsA(const bf16_t* As, bf16_t* Ub, int lane) {
    const int half = lane >> 5;
    const int l31 = lane & 31;
    f32x16 z16;
#pragma unroll
    for (int r = 0; r < 16; r++) z16[r] = 0.0f;

    bf16x8 af[2][3];
#pragma unroll
    for (int mt = 0; mt < 2; mt++) {
        int m = l31 + 32 * mt;
#pragma unroll
        for (int ks = 0; ks < 3; ks++) {
            bf16x8 f;
#pragma unroll
            for (int j = 0; j < 8; j++) {
                int k = 16 * ks + 8 * half + j;
                f[j] = (m < KK) ? As[k * PST + m] : (bf16_t)0.0f;
            }
            af[mt][ks] = f;
        }
    }
    bf16x8 bg[3][2];
#pragma unroll
    for (int ks = 0; ks < 3; ks++)
#pragma unroll
        for (int nt = 0; nt < 2; nt++)
            bg[ks][nt] = __builtin_bit_cast(bf16x8, *(const uint4*)&Ub[(l31 + 32 * nt) * PST + 16 * ks + 8 * half]);

    f32x16 acc[4];
#pragma unroll
    for (int mt = 0; mt < 2; mt++)
#pragma unroll
        for (int nt = 0; nt < 2; nt++) {
            f32x16 a0 = __builtin_amdgcn_mfma_f32_32x32x16_bf16(af[mt][0], bg[0][nt], z16, 0, 0, 0);
            a0 = __builtin_amdgcn_mfma_f32_32x32x16_bf16(af[mt][1], bg[1][nt], a0, 0, 0, 0);
            acc[mt * 2 + nt] = __builtin_amdgcn_mfma_f32_32x32x16_bf16(af[mt][2], bg[2][nt], a0, 0, 0, 0);
        }

    float v00 = rdlanef(acc[0][0], 0);
    int k = (int)(__float_as_uint(v00) >> 23) - 127;
    float r = __uint_as_float((unsigned int)(127 - k) << 23);

#pragma unroll
    for (int mt = 0; mt < 2; mt++)
#pragma unroll
        for (int nt = 0; nt < 2; nt++) {
            int c = l31 + 32 * nt;
#pragma unroll
            for (int g = 0; g < 4; g++) {
                int a0 = 32 * mt + 8 * g + 4 * half;
                if (a0 < KK) {
                    const f32x16& Aq = acc[mt * 2 + nt];
                    unsigned int u0 = bf16bits(Aq[4 * g + 0] * r) | (bf16bits(Aq[4 * g + 1] * r) << 16);
                    unsigned int u1 = bf16bits(Aq[4 * g + 2] * r) | (bf16bits(Aq[4 * g + 3] * r) << 16);
                    *(uint2*)&Ub[c * PST + a0] = make_uint2(u0, u1);
                }
            }
        }
    return k;
}

// ============ fold8: parallel tree fold of 8 consecutive segments per block ============
__global__ __launch_bounds__(256) void fold8_kernel(
    bf16_t* __restrict__ ws_u, int* __restrict__ ws_ls, int nseg) {
    const int s8 = blockIdx.x, b = blockIdx.y;
    const int tid = threadIdx.x;
    const int w = tid >> 6, lane = tid & 63;
    const int base = b * nseg + s8 * 8;

    __shared__ __align__(16) bf16_t Ws[4][64 * PST];   // 4 x 7 KB
    __shared__ int lsp[8];

    {   // pair product: Ws[w] = U_{2w+1} * U_{2w}  (later segment on the left)
        const bf16_t* sE = ws_u + (size_t)(base + 2 * w) * SEGELEMS;
        for (int k = 0; k < KK; k++)
            Ws[w][lane * PST + k] = (lane < KK) ? sE[(size_t)k * 48 + lane] : (bf16_t)0.0f;
        int lsk = ws_ls[base + 2 * w] + ws_ls[base + 2 * w + 1];
        lsk += chain_product(ws_u + (size_t)(base + 2 * w + 1) * SEGELEMS, Ws[w], lane);
        if (lane == 0) lsp[w] = lsk;
    }
    __syncthreads();
    int k1 = 0;
    if (w == 0) k1 = chain_product_ldsA(Ws[1], Ws[0], lane);        // Ws0 = W1*W0
    if (w == 2) {                                                    // Ws2 = W3*W2
        int k2 = chain_product_ldsA(Ws[3], Ws[2], lane);
        if (lane == 0) lsp[5] = k2;
    }
    __syncthreads();
    if (w == 0) {
        int k3 = chain_product_ldsA(Ws[2], Ws[0], lane);             // Ws0 = (W3W2)(W1W0)
        // write folded 48x48 back into slot 'base' (row-major, stride 48)
        if (lane < KK) {
            bf16_t* Uo = ws_u + (size_t)base * SEGELEMS;
            unsigned int wd[24];
#pragma unroll
            for (int j = 0; j < 24; j++) {
                unsigned int lo = (unsigned int)__builtin_bit_cast(unsigned short, Ws[0][(2 * j) * PST + lane]);
                unsigned int hi = (unsigned int)__builtin_bit_cast(unsigned short, Ws[0][(2 * j + 1) * PST + lane]);
                wd[j] = lo | (hi << 16);
            }
#pragma unroll
            for (int g = 0; g < 6; g++)
                *(uint4*)(Uo + (size_t)lane * 48 + 8 * g) =
                    make_uint4(wd[4 * g], wd[4 * g + 1], wd[4 * g + 2], wd[4 * g + 3]);
        }
        if (lane == 0)
            ws_ls[base] = lsp[0] + lsp[1] + lsp[2] + lsp[3] + k1 + lsp[5] + k3;
    }
}

// ============ final: fold the npart partials (tree) + q0 + output ============
__global__ __launch_bounds__(256) void final_kernel(
    const float* __restrict__ y_pred, const bf16_t* __restrict__ ws_u,
    const int* __restrict__ ws_ls, const float* __restrict__ ws_target,
    float* __restrict__ out, int nseg) {
    const int b = blockIdx.x;
    const int tid = threadIdx.x;
    const int w = tid >> 6, lane = tid & 63;
    const int npart = nseg / 8;            // 2 or 4

    __shared__ __align__(16) bf16_t Ws[4][64 * PST];
    __shared__ int lsp[8];
    if (tid < 8) lsp[tid] = 0;
    __syncthreads();

    if (2 * w < npart) {                   // pair product on partials 2w, 2w+1
        const int slotE = b * nseg + 16 * w;
        const int slotL = slotE + 8;
        const bf16_t* sE = ws_u + (size_t)slotE * SEGELEMS;
        for (int k = 0; k < KK; k++)
            Ws[w][lane * PST + k] = (lane < KK) ? sE[(size_t)k * 48 + lane] : (bf16_t)0.0f;
        int lsk = ws_ls[slotE] + ws_ls[slotL];
        lsk += chain_product(ws_u + (size_t)slotL * SEGELEMS, Ws[w], lane);
        if (lane == 0) lsp[w] = lsk;
    }
    __syncthreads();
    int k1 = 0;
    if (npart >= 4 && w == 0) k1 = chain_product_ldsA(Ws[1], Ws[0], lane);
    if (npart == 8 && w == 2) {
        int k2 = chain_product_ldsA(Ws[3], Ws[2], lane);
        if (lane == 0) lsp[5] = k2;
    }
    __syncthreads();

    if (w == 0) {
        int k3 = 0;
        if (npart == 8) k3 = chain_product_ldsA(Ws[2], Ws[0], lane);
        float L = (float)(lsp[0] + lsp[1] + lsp[2] + lsp[3] + k1 + lsp[5] + k3);

        // q0 from t=0 row
        float x0 = (lane < KK) ? y_pred[(size_t)b * TT * KK + lane] : 0.0f;
        bool ok0 = (lane >= KK) || (x0 > -1e6f);
        bool m0 = (__ballot(ok0) == ~0ull);
        float xeff = (lane < KK) ? (m0 ? x0 : 0.0f) : 0.0f;
        float c0 = rdlanef(xeff, 0);
        float q0 = (lane < KK) ? fexp(xeff - c0) : 0.0f;

        float p = 0.0f;
        if (lane < KK) {
            for (int c = 0; c < KK; c++) {
                float qc = rdlanef(q0, c);
                p = fmaf(bf2f(Ws[0][c * PST + lane]), qc, p);
            }
        }
#pragma unroll
        for (int off = 32; off; off >>= 1) p += __shfl_xor(p, off);

        // target = sum of per-block partials
        float tg = (lane < nseg) ? ws_target[b * nseg + lane] : 0.0f;
#pragma unroll
        for (int off = 32; off; off >>= 1) tg += __shfl_xor(tg, off);

        if (lane == 0) {
            out[b] = c0 + 0.6931471805599453f * (L + flog2(p)) - tg;
        }
    }
}

extern "C" void kernel_launch(void* const* d_in, const int* in_sizes, int n_in,
                              void* d_out, int out_size, void* d_ws, size_t ws_size,
                              hipStream_t stream) {
    const float* y_true = (const float*)d_in[0];
    const float* y_pred = (const float*)d_in[1];
    const float* trans = (const float*)d_in[2];
    float* out = (float*)d_out;

    // adaptive segment count (never overrun d_ws). Tiers: 16 / 32 only — the
    // in-block split needs seglen >= 128 (nseg <= 32).
    int nseg = 16;
    if (ws_size >= (size_t)WS_U_OFF + (size_t)BB * 32 * SEGBYTES) nseg = 32;

    float* ws_target = (float*)d_ws;                          // BB*nseg floats (<=16 KB)
    int* ws_ls = (int*)((char*)d_ws + WS_LS_OFF);             // BB*nseg ints  (<=16 KB)
    bf16_t* ws_u = (bf16_t*)((char*)d_ws + WS_U_OFF);

    fused_kernel<<<dim3(nseg, BB), 512, 0, stream>>>(
        y_true, y_pred, trans, ws_target, ws_ls, ws_u, nseg);
    fold8_kernel<<<dim3(nseg / 8, BB), 256, 0, stream>>>(ws_u, ws_ls, nseg);
    final_kernel<<<BB, 256, 0, stream>>>(y_pred, ws_u, ws_ls, ws_target, out, nseg);
}

// Round 9
// 257.613 us; speedup vs baseline: 1.0331x; 1.0033x over previous
//
#include <hip/hip_runtime.h>

#define BB 64
#define TT 4096
#define KK 48
#define UST 56              // Ubuf col stride (bf16): 112 B. MUST be mult of 8 elems
                            // (16 B): r5's UST=58 misaligned ds_read_b128 -> 3.6x slower.
#define PST 56              // phase LDS col stride (bf16)
#define WS_LS_OFF 16384
#define WS_U_OFF 32768
#define SEGBYTES 4608       // compact: 48 rows x 48 col-stride x bf16
#define SEGELEMS 2304

typedef __bf16 bf16_t;
typedef bf16_t bf16x8 __attribute__((ext_vector_type(8)));
typedef float f32x4 __attribute__((ext_vector_type(4)));
typedef float f32x16 __attribute__((ext_vector_type(16)));

__device__ __forceinline__ float fexp(float x) {   // natural exp
    return __builtin_amdgcn_exp2f(x * 1.4426950408889634f);
}
__device__ __forceinline__ float flog2(float x) { return __builtin_amdgcn_logf(x); }
__device__ __forceinline__ float rdlanef(float v, int l) {
    return __int_as_float(__builtin_amdgcn_readlane(__float_as_int(v), l));
}
__device__ __forceinline__ unsigned int bf16bits(float f) {
    return (unsigned int)__builtin_bit_cast(unsigned short, (bf16_t)f);
}
__device__ __forceinline__ float bf2f(bf16_t h) {
    return __uint_as_float(((unsigned int)__builtin_bit_cast(unsigned short, h)) << 16);
}
// pack two fp32 -> bf16x2 by truncation (1 v_perm_b32); lo in low half
__device__ __forceinline__ unsigned int pktrunc(float lo, float hi) {
    return __builtin_amdgcn_perm(__float_as_uint(hi), __float_as_uint(lo), 0x07060302u);
}

// ============ fused: 8-wave block = 2 parallel half-chains + in-block compose ====
// r9: r8 structure with (512,5). r8's (512,4) gave the allocator a 64-reg budget
// and it used all 64 -> empirically the 64-reg boundary halves waves/CU to 16
// (r8 occupancy 42.6%, fused 159us = r6's 12 chain-waves/CU + compose overhead).
// The chain itself fits in 48 regs (r3/r6 at (256,4) allocated 48). Budget 51
// ((512,5)) keeps the hot loop unspilled and lands below the 64-reg cliff ->
// 32 waves/CU (LDS 37.9KB -> 4 blocks x 8 waves; grid = exactly 4 blocks/CU).
// Spill, if any, is confined to the cold once-per-block compose epilogue.
// Check: WRITE_SIZE must stay ~9.3MB (r7's hot-loop spill was 194MB).
__global__ __launch_bounds__(512, 5) void fused_kernel(
    const float* __restrict__ y_true, const float* __restrict__ y_pred,
    const float* __restrict__ trans, float* __restrict__ ws_target,
    int* __restrict__ ws_ls, bf16_t* __restrict__ ws_u, int nseg) {
    const int s = blockIdx.x, b = blockIdx.y;
    const int seglen = TT / nseg;
    const int nch_sub = seglen / 128;       // chunks per sub-chain (>=1 for nseg<=32)
    const int tid = threadIdx.x;
    const int w = tid >> 6;                 // 0..7
    const int sub = w >> 2;                 // sub-chain id 0/1
    const int wl = w & 3;                   // role within sub-chain: 0-2 chain, 3 producer
    const int lane = tid & 63;
    const int q = lane >> 4;
    const int n = lane & 15;
    const int ncol = 16 * wl + n;

    __shared__ __align__(16) float4 exf[2][64 * 13];          // fp32 ex per sub-chain
    __shared__ __align__(16) bf16_t Ubuf[2][48 * UST + 16];   // U state per sub-chain
    __shared__ unsigned long long pb[2];
    __shared__ int lsbA[4], lsbB[4];
    __shared__ float scpart[2];

    // A fragments (chain waves of both subs): E^T zero-padded in K.
    bf16x8 afrag[3][2];
    if (wl < 3) {
#pragma unroll
        for (int mt = 0; mt < 3; mt++) {
#pragma unroll
            for (int ks = 0; ks < 2; ks++) {
                bf16x8 f;
#pragma unroll
                for (int j = 0; j < 8; j++) {
                    int k = 32 * ks + 8 * q + j;
                    float v = (k < KK) ? fexp(trans[k * KK + 16 * mt + n]) : 0.0f;
                    f[j] = (bf16_t)v;
                }
                afrag[mt][ks] = f;
            }
        }
    }

    {   // zero both Ubufs then identity diags
        uint4* p = (uint4*)&Ubuf[0][0];
        const int nq = 2 * (48 * UST + 16) / 8;
        for (int i = tid; i < nq; i += 512) p[i] = make_uint4(0, 0, 0, 0);
    }
    __syncthreads();
    if (tid < KK) {
        Ubuf[0][tid * UST + tid] = (bf16_t)1.0f;
        Ubuf[1][tid * UST + tid] = (bf16_t)1.0f;
    }

    const bf16_t* bptr0 = &Ubuf[sub][ncol * UST + 8 * q];
    const bf16_t* bptr1 = &Ubuf[sub][ncol * UST + 32 + 8 * q];
    bf16_t* wp0 = &Ubuf[sub][ncol * UST + 0 + 4 * q];
    bf16_t* wp1 = &Ubuf[sub][ncol * UST + 16 + 4 * q];
    bf16_t* wp2 = &Ubuf[sub][ncol * UST + 32 + 4 * q];

    f32x4 z4 = {0.0f, 0.0f, 0.0f, 0.0f};
    int ls = 0;
    int cnt = 0;          // unmasked steps since last rescale (wave-uniform)
    float sc_acc = 0.0f;  // producers: scores accumulator

    for (int ch = 0; ch < nch_sub; ch++) {
        __syncthreads();                     // previous exf fully consumed
        if (wl == 3) {
            // ---- producer + scores: lane = local timestep ----
            const int gch = sub * nch_sub + ch;
            const int t0c = s * seglen + gch * 64;
            const size_t rowbase = ((size_t)b * TT + t0c + lane) * KK;
            const float4* yp4 = (const float4*)(y_pred + rowbase);
            const float4* yt4 = (const float4*)(y_true + rowbase);
            float dot = 0.0f, labf = 0.0f, pmin = 1e30f;
            float4* exrow = &exf[sub][lane * 13];
#pragma unroll 4
            for (int g = 0; g < 12; g++) {
                float4 p = yp4[g];
                float4 a = yt4[g];
                dot = fmaf(a.x, p.x, fmaf(a.y, p.y, fmaf(a.z, p.z, fmaf(a.w, p.w, dot))));
                float e0 = (float)(4 * g);
                labf = fmaf(a.x, e0, fmaf(a.y, e0 + 1.0f, fmaf(a.z, e0 + 2.0f, fmaf(a.w, e0 + 3.0f, labf))));
                pmin = fminf(pmin, fminf(fminf(p.x, p.y), fminf(p.z, p.w)));
                exrow[g] = make_float4(fexp(p.x), fexp(p.y), fexp(p.z), fexp(p.w));
            }
            bool mt_ok = pmin > -1e6f;
            unsigned long long bal = __ballot(mt_ok);
            if (lane == 0) pb[sub] = bal;

            // boundary row t0c+64 (label+mask), lanes 0..11 partials
            float labB = 0.0f, pmB = 1e30f;
            const bool hasB = (t0c + 64 < TT);
            if (hasB && lane < 12) {
                const size_t bdbase = ((size_t)b * TT + t0c + 64) * KK;
                float4 a = ((const float4*)(y_true + bdbase))[lane];
                float4 p = ((const float4*)(y_pred + bdbase))[lane];
                float e0 = (float)(4 * lane);
                labB = fmaf(a.x, e0, fmaf(a.y, e0 + 1.0f, fmaf(a.z, e0 + 2.0f, a.w * (e0 + 3.0f))));
                pmB = fminf(fminf(p.x, p.y), fminf(p.z, p.w));
            }
#pragma unroll
            for (int off = 1; off < 16; off <<= 1) {
                labB += __shfl_xor(labB, off);
                pmB = fminf(pmB, __shfl_xor(pmB, off));
            }
            int labB_i = (int)(rdlanef(labB, 0) + 0.5f);
            float mB = (hasB && rdlanef(pmB, 0) > -1e6f) ? 1.0f : 0.0f;

            int labt = (int)(labf + 0.5f);
            float mft = mt_ok ? 1.0f : 0.0f;
            int lnx = __shfl(labt, (lane + 1) & 63);
            float mnx = __shfl(mft, (lane + 1) & 63);
            if (lane == 63) { lnx = labB_i; mnx = mB; }
            sc_acc += mft * dot + mft * mnx * trans[labt * KK + lnx];
        }
        __syncthreads();
        if (wl < 3) {
            const unsigned long long mk = pb[sub];
            const int tt0 = (s == 0 && sub == 0 && ch == 0) ? 1 : 0;
            for (int tt = tt0; tt < 64; tt++) {
                if (!((mk >> tt) & 1ull)) continue;

                bf16x8 bf0 = __builtin_bit_cast(bf16x8, *(const uint4*)bptr0);
                bf16x8 bf1 = __builtin_bit_cast(bf16x8, *(const uint4*)bptr1);

                f32x4 acc0 = __builtin_amdgcn_mfma_f32_16x16x32_bf16(afrag[0][0], bf0, z4, 0, 0, 0);
                acc0 = __builtin_amdgcn_mfma_f32_16x16x32_bf16(afrag[0][1], bf1, acc0, 0, 0, 0);
                f32x4 acc1 = __builtin_amdgcn_mfma_f32_16x16x32_bf16(afrag[1][0], bf0, z4, 0, 0, 0);
                acc1 = __builtin_amdgcn_mfma_f32_16x16x32_bf16(afrag[1][1], bf1, acc1, 0, 0, 0);
                f32x4 acc2 = __builtin_amdgcn_mfma_f32_16x16x32_bf16(afrag[2][0], bf0, z4, 0, 0, 0);
                acc2 = __builtin_amdgcn_mfma_f32_16x16x32_bf16(afrag[2][1], bf1, acc2, 0, 0, 0);

                // deferred pow2 rescale: every 6 unmasked steps (overflow-safe;
                // per-step growth < 2^13, 6 steps < 2^78 << fp32/bf16 max 2^127).
                if (++cnt >= 6) {
                    float v00 = rdlanef(acc0[0], 0);
                    int k = (int)(__float_as_uint(v00) >> 23) - 127;
                    float r = __uint_as_float((unsigned int)(127 - k) << 23);
                    ls += k;
                    cnt = 0;
                    float4 ex0 = exf[sub][tt * 13 + q];
                    ex0.x *= r; ex0.y *= r; ex0.z *= r; ex0.w *= r;
                    *(uint2*)wp0 = make_uint2(pktrunc(acc0[0] * ex0.x, acc0[1] * ex0.y),
                                              pktrunc(acc0[2] * ex0.z, acc0[3] * ex0.w));
                    float4 ex1 = exf[sub][tt * 13 + 4 + q];
                    ex1.x *= r; ex1.y *= r; ex1.z *= r; ex1.w *= r;
                    *(uint2*)wp1 = make_uint2(pktrunc(acc1[0] * ex1.x, acc1[1] * ex1.y),
                                              pktrunc(acc1[2] * ex1.z, acc1[3] * ex1.w));
                    float4 ex2 = exf[sub][tt * 13 + 8 + q];
                    ex2.x *= r; ex2.y *= r; ex2.z *= r; ex2.w *= r;
                    *(uint2*)wp2 = make_uint2(pktrunc(acc2[0] * ex2.x, acc2[1] * ex2.y),
                                              pktrunc(acc2[2] * ex2.z, acc2[3] * ex2.w));
                } else {
                    float4 ex0 = exf[sub][tt * 13 + q];
                    *(uint2*)wp0 = make_uint2(pktrunc(acc0[0] * ex0.x, acc0[1] * ex0.y),
                                              pktrunc(acc0[2] * ex0.z, acc0[3] * ex0.w));
                    float4 ex1 = exf[sub][tt * 13 + 4 + q];
                    *(uint2*)wp1 = make_uint2(pktrunc(acc1[0] * ex1.x, acc1[1] * ex1.y),
                                              pktrunc(acc1[2] * ex1.z, acc1[3] * ex1.w));
                    float4 ex2 = exf[sub][tt * 13 + 8 + q];
                    *(uint2*)wp2 = make_uint2(pktrunc(acc2[0] * ex2.x, acc2[1] * ex2.y),
                                              pktrunc(acc2[2] * ex2.z, acc2[3] * ex2.w));
                }
            }
        }
    }

    __syncthreads();                         // both half-chains done; exf dead
    // stash sub-chain B scales + per-sub scores
    if (sub == 1 && wl < 3 && lane == 0) lsbB[wl] = ls;
    if (wl == 3) {
#pragma unroll
        for (int off = 32; off; off >>= 1) sc_acc += __shfl_xor(sc_acc, off);
        if (lane == 0) scpart[sub] = sc_acc;
    }
    // RB = row-major U_B staging (stride 64, cols 48-63 zeroed), overlaid on exf[1]
    bf16_t* RB = (bf16_t*)&exf[1][0];        // 6144 B <= 13312 B region
    __syncthreads();
    {   // zero RB (incl. pad cols used as zero K-tail by the fold MFMA)
        uint4* rp = (uint4*)RB;
        for (int i = tid; i < 384; i += 512) rp[i] = make_uint4(0, 0, 0, 0);
    }
    __syncthreads();
    // waves 4-6: reconcile U_B (per-wave pow2 scales -> lsbB[0]) into RB row-major
    if (sub == 1 && wl < 3 && lane < KK) {
        const int dl = ls - lsbB[0];
        unsigned int wd[8];
#pragma unroll
        for (int j = 0; j < 8; j++) {
            float f0 = ldexpf(bf2f(Ubuf[1][(16 * wl + 2 * j) * UST + lane]), dl);
            float f1 = ldexpf(bf2f(Ubuf[1][(16 * wl + 2 * j + 1) * UST + lane]), dl);
            wd[j] = bf16bits(f0) | (bf16bits(f1) << 16);
        }
        *(uint4*)(RB + lane * 64 + 16 * wl) = make_uint4(wd[0], wd[1], wd[2], wd[3]);
        *(uint4*)(RB + lane * 64 + 16 * wl + 8) = make_uint4(wd[4], wd[5], wd[6], wd[7]);
    }
    __syncthreads();
    // fold: waves 0-2 run ONE chain-like step with A-frags = U_B (rows 16mt+n,
    // k = 32ks+8q+j from RB row-major), B = U_A columns (bptr0/1), forced rescale.
    // Result overwrites Ubuf[0]; per-wave k folds into existing lsb mechanism.
    if (sub == 0 && wl < 3) {
        bf16x8 aB0, aB1, bf0, bf1;
        bf0 = __builtin_bit_cast(bf16x8, *(const uint4*)bptr0);
        bf1 = __builtin_bit_cast(bf16x8, *(const uint4*)bptr1);
        aB0 = __builtin_bit_cast(bf16x8, *(const uint4*)&RB[(16 * 0 + n) * 64 + 8 * q]);
        aB1 = __builtin_bit_cast(bf16x8, *(const uint4*)&RB[(16 * 0 + n) * 64 + 32 + 8 * q]);
        f32x4 acc0 = __builtin_amdgcn_mfma_f32_16x16x32_bf16(aB0, bf0, z4, 0, 0, 0);
        acc0 = __builtin_amdgcn_mfma_f32_16x16x32_bf16(aB1, bf1, acc0, 0, 0, 0);
        aB0 = __builtin_bit_cast(bf16x8, *(const uint4*)&RB[(16 * 1 + n) * 64 + 8 * q]);
        aB1 = __builtin_bit_cast(bf16x8, *(const uint4*)&RB[(16 * 1 + n) * 64 + 32 + 8 * q]);
        f32x4 acc1 = __builtin_amdgcn_mfma_f32_16x16x32_bf16(aB0, bf0, z4, 0, 0, 0);
        acc1 = __builtin_amdgcn_mfma_f32_16x16x32_bf16(aB1, bf1, acc1, 0, 0, 0);
        aB0 = __builtin_bit_cast(bf16x8, *(const uint4*)&RB[(16 * 2 + n) * 64 + 8 * q]);
        aB1 = __builtin_bit_cast(bf16x8, *(const uint4*)&RB[(16 * 2 + n) * 64 + 32 + 8 * q]);
        f32x4 acc2 = __builtin_amdgcn_mfma_f32_16x16x32_bf16(aB0, bf0, z4, 0, 0, 0);
        acc2 = __builtin_amdgcn_mfma_f32_16x16x32_bf16(aB1, bf1, acc2, 0, 0, 0);

        float v00 = rdlanef(acc0[0], 0);
        int k = (int)(__float_as_uint(v00) >> 23) - 127;
        float r = __uint_as_float((unsigned int)(127 - k) << 23);
        ls += k;
        *(uint2*)wp0 = make_uint2(pktrunc(acc0[0] * r, acc0[1] * r),
                                  pktrunc(acc0[2] * r, acc0[3] * r));
        *(uint2*)wp1 = make_uint2(pktrunc(acc1[0] * r, acc1[1] * r),
                                  pktrunc(acc1[2] * r, acc1[3] * r));
        *(uint2*)wp2 = make_uint2(pktrunc(acc2[0] * r, acc2[1] * r),
                                  pktrunc(acc2[2] * r, acc2[3] * r));
    }
    if (sub == 0 && wl < 3 && lane == 0) lsbA[wl] = ls;
    __syncthreads();
    // epilogue: waves 0-2 reconcile + write compact 48x48 bf16 block
    if (sub == 0 && wl < 3 && lane < KK) {
        const int dl = ls - lsbA[0];
        bf16_t* Uo = ws_u + (size_t)(b * nseg + s) * SEGELEMS;
        unsigned int wd[8];
#pragma unroll
        for (int j = 0; j < 8; j++) {
            float f0 = ldexpf(bf2f(Ubuf[0][(16 * wl + 2 * j) * UST + lane]), dl);
            float f1 = ldexpf(bf2f(Ubuf[0][(16 * wl + 2 * j + 1) * UST + lane]), dl);
            wd[j] = bf16bits(f0) | (bf16bits(f1) << 16);
        }
        *(uint4*)(Uo + (size_t)lane * 48 + 16 * wl) = make_uint4(wd[0], wd[1], wd[2], wd[3]);
        *(uint4*)(Uo + (size_t)lane * 48 + 16 * wl + 8) = make_uint4(wd[4], wd[5], wd[6], wd[7]);
    }
    if (tid == 0) {
        ws_ls[b * nseg + s] = lsbA[0] + lsbB[0];
        ws_target[b * nseg + s] = scpart[0] + scpart[1];
    }
}

// 48x48 product: D = A (global row-major 48x48) x W (LDS col-major stride PST), in place.
// Returns pow2 scale exponent removed. No barriers inside (single-wave safe).
__device__ __forceinline__ int chain_product(const bf16_t* __restrict__ A, bf16_t* Ub, int lane) {
    const int half = lane >> 5;
    const int l31 = lane & 31;
    f32x16 z16;
#pragma unroll
    for (int r = 0; r < 16; r++) z16[r] = 0.0f;

    bf16x8 af[2][3];
#pragma unroll
    for (int mt = 0; mt < 2; mt++) {
        int m = l31 + 32 * mt;
#pragma unroll
        for (int ks = 0; ks < 3; ks++) {
            if (m < KK)
                af[mt][ks] = __builtin_bit_cast(bf16x8, *(const uint4*)&A[(size_t)m * 48 + 16 * ks + 8 * half]);
            else
                af[mt][ks] = __builtin_bit_cast(bf16x8, make_uint4(0, 0, 0, 0));
        }
    }
    bf16x8 bg[3][2];
#pragma unroll
    for (int ks = 0; ks < 3; ks++)
#pragma unroll
        for (int nt = 0; nt < 2; nt++)
            bg[ks][nt] = __builtin_bit_cast(bf16x8, *(const uint4*)&Ub[(l31 + 32 * nt) * PST + 16 * ks + 8 * half]);

    f32x16 acc[4];
#pragma unroll
    for (int mt = 0; mt < 2; mt++)
#pragma unroll
        for (int nt = 0; nt < 2; nt++) {
            f32x16 a0 = __builtin_amdgcn_mfma_f32_32x32x16_bf16(af[mt][0], bg[0][nt], z16, 0, 0, 0);
            a0 = __builtin_amdgcn_mfma_f32_32x32x16_bf16(af[mt][1], bg[1][nt], a0, 0, 0, 0);
            acc[mt * 2 + nt] = __builtin_amdgcn_mfma_f32_32x32x16_bf16(af[mt][2], bg[2][nt], a0, 0, 0, 0);
        }

    float v00 = rdlanef(acc[0][0], 0);
    int k = (int)(__float_as_uint(v00) >> 23) - 127;
    float r = __uint_as_float((unsigned int)(127 - k) << 23);

#pragma unroll
    for (int mt = 0; mt < 2; mt++)
#pragma unroll
        for (int nt = 0; nt < 2; nt++) {
            int c = l31 + 32 * nt;
#pragma unroll
            for (int g = 0; g < 4; g++) {
                int a0 = 32 * mt + 8 * g + 4 * half;
                if (a0 < KK) {
                    const f32x16& Aq = acc[mt * 2 + nt];
                    unsigned int u0 = bf16bits(Aq[4 * g + 0] * r) | (bf16bits(Aq[4 * g + 1] * r) << 16);
                    unsigned int u1 = bf16bits(Aq[4 * g + 2] * r) | (bf16bits(Aq[4 * g + 3] * r) << 16);
                    *(uint2*)&Ub[c * PST + a0] = make_uint2(u0, u1);
                }
            }
        }
    return k;
}

// Variant: A read from LDS col-major slot (A[m][k] = As[k*PST + m]).
__device__ __forceinline__ int chain_product_ldsA(const bf16_t* As, bf16_t* Ub, int lane) {
    const int half = lane >> 5;
    const int l31 = lane & 31;
    f32x16 z16;
#pragma unroll
    for (int r = 0; r < 16; r++) z16[r] = 0.0f;

    bf16x8 af[2][3];
#pragma unroll
    for (int mt = 0; mt < 2; mt++) {
        int m = l31 + 32 * mt;
#pragma unroll
        for (int ks = 0; ks < 3; ks++) {
            bf16x8 f;
#pragma unroll
            for (int j = 0; j < 8; j++) {
                int k = 16 * ks + 8 * half + j;
                f[j] = (m < KK) ? As[k * PST + m] : (bf16_t)0.0f;
            }
            af[mt][ks] = f;
        }
    }
    bf16x8 bg[3][2];
#pragma unroll
    for (int ks = 0; ks < 3; ks++)
#pragma unroll
        for (int nt = 0; nt < 2; nt++)
            bg[ks][nt] = __builtin_bit_cast(bf16x8, *(const uint4*)&Ub[(l31 + 32 * nt) * PST + 16 * ks + 8 * half]);

    f32x16 acc[4];
#pragma unroll
    for (int mt = 0; mt < 2; mt++)
#pragma unroll
        for (int nt = 0; nt < 2; nt++) {
            f32x16 a0 = __builtin_amdgcn_mfma_f32_32x32x16_bf16(af[mt][0], bg[0][nt], z16, 0, 0, 0);
            a0 = __builtin_amdgcn_mfma_f32_32x32x16_bf16(af[mt][1], bg[1][nt], a0, 0, 0, 0);
            acc[mt * 2 + nt] = __builtin_amdgcn_mfma_f32_32x32x16_bf16(af[mt][2], bg[2][nt], a0, 0, 0, 0);
        }

    float v00 = rdlanef(acc[0][0], 0);
    int k = (int)(__float_as_uint(v00) >> 23) - 127;
    float r = __uint_as_float((unsigned int)(127 - k) << 23);

#pragma unroll
    for (int mt = 0; mt < 2; mt++)
#pragma unroll
        for (int nt = 0; nt < 2; nt++) {
            int c = l31 + 32 * nt;
#pragma unroll
            for (int g = 0; g < 4; g++) {
                int a0 = 32 * mt + 8 * g + 4 * half;
                if (a0 < KK) {
                    const f32x16& Aq = acc[mt * 2 + nt];
                    unsigned int u0 = bf16bits(Aq[4 * g + 0] * r) | (bf16bits(Aq[4 * g + 1] * r) << 16);
                    unsigned int u1 = bf16bits(Aq[4 * g + 2] * r) | (bf16bits(Aq[4 * g + 3] * r) << 16);
                    *(uint2*)&Ub[c * PST + a0] = make_uint2(u0, u1);
                }
            }
        }
    return k;
}

// ============ fold_final: merged fold8+final — one launch instead of two ==========
// grid B, 256 threads. Wave w serially folds its nseg/4 consecutive slots into
// Ws[w] (3 products for nseg=16), then verified 4->2->1 tree + q0 + output.
// Saves one kernel launch and the partials' global-memory round trip.
__global__ __launch_bounds__(256) void fold_final_kernel(
    const float* __restrict__ y_pred, const bf16_t* __restrict__ ws_u,
    const int* __restrict__ ws_ls, const float* __restrict__ ws_target,
    float* __restrict__ out, int nseg) {
    const int b = blockIdx.x;
    const int tid = threadIdx.x;
    const int w = tid >> 6, lane = tid & 63;
    const int per = nseg / 4;              // 4 (nseg=16) or 8 (nseg=32)

    __shared__ __align__(16) bf16_t Ws[4][64 * PST];
    __shared__ int lsp[8];
    if (tid < 8) lsp[tid] = 0;
    __syncthreads();

    {   // wave w: fold slots [base, base+per) serially (later segment on the left)
        const int base = b * nseg + per * w;
        const bf16_t* s0 = ws_u + (size_t)base * SEGELEMS;
        for (int k = 0; k < KK; k++)
            Ws[w][lane * PST + k] = (lane < KK) ? s0[(size_t)k * 48 + lane] : (bf16_t)0.0f;
        int lsk = ws_ls[base];
        for (int j = 1; j < per; j++) {
            lsk += ws_ls[base + j];
            lsk += chain_product(ws_u + (size_t)(base + j) * SEGELEMS, Ws[w], lane);
        }
        if (lane == 0) lsp[w] = lsk;
    }
    __syncthreads();
    int k1 = 0;
    if (w == 0) k1 = chain_product_ldsA(Ws[1], Ws[0], lane);        // Ws0 = W1*W0
    if (w == 2) {                                                    // Ws2 = W3*W2
        int k2 = chain_product_ldsA(Ws[3], Ws[2], lane);
        if (lane == 0) lsp[5] = k2;
    }
    __syncthreads();

    if (w == 0) {
        int k3 = chain_product_ldsA(Ws[2], Ws[0], lane);             // Ws0 = (W3W2)(W1W0)
        float L = (float)(lsp[0] + lsp[1] + lsp[2] + lsp[3] + k1 + lsp[5] + k3);

        // q0 from t=0 row
        float x0 = (lane < KK) ? y_pred[(size_t)b * TT * KK + lane] : 0.0f;
        bool ok0 = (lane >= KK) || (x0 > -1e6f);
        bool m0 = (__ballot(ok0) == ~0ull);
        float xeff = (lane < KK) ? (m0 ? x0 : 0.0f) : 0.0f;
        float c0 = rdlanef(xeff, 0);
        float q0 = (lane < KK) ? fexp(xeff - c0) : 0.0f;

        float p = 0.0f;
        if (lane < KK) {
            for (int c = 0; c < KK; c++) {
                float qc = rdlanef(q0, c);
                p = fmaf(bf2f(Ws[0][c * PST + lane]), qc, p);
            }
        }
#pragma unroll
        for (int off = 32; off; off >>= 1) p += __shfl_xor(p, off);

        // target = sum of per-block partials
        float tg = (lane < nseg) ? ws_target[b * nseg + lane] : 0.0f;
#pragma unroll
        for (int off = 32; off; off >>= 1) tg += __shfl_xor(tg, off);

        if (lane == 0) {
            out[b] = c0 + 0.6931471805599453f * (L + flog2(p)) - tg;
        }
    }
}

extern "C" void kernel_launch(void* const* d_in, const int* in_sizes, int n_in,
                              void* d_out, int out_size, void* d_ws, size_t ws_size,
                              hipStream_t stream) {
    const float* y_true = (const float*)d_in[0];
    const float* y_pred = (const float*)d_in[1];
    const float* trans = (const float*)d_in[2];
    float* out = (float*)d_out;

    // adaptive segment count (never overrun d_ws). Tiers: 16 / 32 only — the
    // in-block split needs seglen >= 128 (nseg <= 32).
    int nseg = 16;
    if (ws_size >= (size_t)WS_U_OFF + (size_t)BB * 32 * SEGBYTES) nseg = 32;

    float* ws_target = (float*)d_ws;                          // BB*nseg floats (<=16 KB)
    int* ws_ls = (int*)((char*)d_ws + WS_LS_OFF);             // BB*nseg ints  (<=16 KB)
    bf16_t* ws_u = (bf16_t*)((char*)d_ws + WS_U_OFF);

    fused_kernel<<<dim3(nseg, BB), 512, 0, stream>>>(
        y_true, y_pred, trans, ws_target, ws_ls, ws_u, nseg);
    fold_final_kernel<<<BB, 256, 0, stream>>>(y_pred, ws_u, ws_ls, ws_target, out, nseg);
}

// Round 10
// 235.748 us; speedup vs baseline: 1.1289x; 1.0928x over previous
//
#include <hip/hip_runtime.h>

#define BB 64
#define TT 4096
#define KK 48
#define UST 56              // Ubuf col stride (bf16): 112 B. MUST be mult of 8 elems
                            // (16 B): r5's UST=58 misaligned ds_read_b128 -> 3.6x slower.
#define PST 56              // phase LDS col stride (bf16)
#define WS_LS_OFF 16384
#define WS_U_OFF 32768
#define SEGBYTES 4608       // compact: 48 rows x 48 col-stride x bf16
#define SEGELEMS 2304

typedef __bf16 bf16_t;
typedef bf16_t bf16x8 __attribute__((ext_vector_type(8)));
typedef float f32x4 __attribute__((ext_vector_type(4)));
typedef float f32x16 __attribute__((ext_vector_type(16)));

__device__ __forceinline__ float fexp(float x) {   // natural exp
    return __builtin_amdgcn_exp2f(x * 1.4426950408889634f);
}
__device__ __forceinline__ float flog2(float x) { return __builtin_amdgcn_logf(x); }
__device__ __forceinline__ float rdlanef(float v, int l) {
    return __int_as_float(__builtin_amdgcn_readlane(__float_as_int(v), l));
}
__device__ __forceinline__ unsigned int bf16bits(float f) {
    return (unsigned int)__builtin_bit_cast(unsigned short, (bf16_t)f);
}
__device__ __forceinline__ float bf2f(bf16_t h) {
    return __uint_as_float(((unsigned int)__builtin_bit_cast(unsigned short, h)) << 16);
}
// pack two fp32 -> bf16x2 by truncation (1 v_perm_b32); lo in low half
__device__ __forceinline__ unsigned int pktrunc(float lo, float hi) {
    return __builtin_amdgcn_perm(__float_as_uint(hi), __float_as_uint(lo), 0x07060302u);
}

// ============ fused: r6 structure + producer/chain double-buffer overlap ==========
// r10: 512-thread shape abandoned (r7 spill / r8 64-reg cliff / r9 VGPR=48 but
// occupancy STILL 43% -> LDS-granularity caps 512t blocks at ~2/CU; no reg tuning
// fixes that). Back to verified r6: 256 threads, (256,4), VGPR 48, 133 us.
// New: exf/pb DOUBLE-BUFFERED so the producer wave fills chunk ch+1 while the 3
// chain waves consume chunk ch. Previously producer and chain strictly alternated
// (each idle while the other ran). Identical ops/order/values — producer output
// just lands one iteration earlier in the other buffer. LDS 18.9->32.1 KB, still
// >=4 blocks/CU (grid caps at 4: nseg*BB=1024 blocks / 256 CU).
__global__ __launch_bounds__(256, 4) void fused_kernel(
    const float* __restrict__ y_true, const float* __restrict__ y_pred,
    const float* __restrict__ trans, float* __restrict__ ws_target,
    int* __restrict__ ws_ls, bf16_t* __restrict__ ws_u, int nseg) {
    const int s = blockIdx.x, b = blockIdx.y;
    const int seglen = TT / nseg;
    const int nch = seglen / 64;
    const int tid = threadIdx.x;
    const int w = tid >> 6;
    const int lane = tid & 63;
    const int q = lane >> 4;
    const int n = lane & 15;
    const int ncol = 16 * w + n;

    __shared__ __align__(16) float4 exf[2][64 * 13];          // fp32 ex, ping-pong
    __shared__ __align__(16) bf16_t Ubuf[48 * UST + 16];
    __shared__ unsigned long long pbb[2];
    __shared__ int lsb[4];

    // A fragments (waves 0-2): E^T zero-padded in K. A[m][k]: m=16mt+n, k=32ks+8q+j.
    bf16x8 afrag[3][2];
    if (w < 3) {
#pragma unroll
        for (int mt = 0; mt < 3; mt++) {
#pragma unroll
            for (int ks = 0; ks < 2; ks++) {
                bf16x8 f;
#pragma unroll
                for (int j = 0; j < 8; j++) {
                    int k = 32 * ks + 8 * q + j;
                    float v = (k < KK) ? fexp(trans[k * KK + 16 * mt + n]) : 0.0f;
                    f[j] = (bf16_t)v;
                }
                afrag[mt][ks] = f;
            }
        }
    }

    {   // zero Ubuf then identity diag
        uint4* p = (uint4*)Ubuf;
        for (int i = tid; i < (48 * UST + 16) / 8; i += 256) p[i] = make_uint4(0, 0, 0, 0);
    }
    __syncthreads();
    if (tid < KK) Ubuf[tid * UST + tid] = (bf16_t)1.0f;

    const bf16_t* bptr0 = &Ubuf[ncol * UST + 8 * q];
    const bf16_t* bptr1 = &Ubuf[ncol * UST + 32 + 8 * q];
    bf16_t* wp0 = &Ubuf[ncol * UST + 0 + 4 * q];
    bf16_t* wp1 = &Ubuf[ncol * UST + 16 + 4 * q];
    bf16_t* wp2 = &Ubuf[ncol * UST + 32 + 4 * q];

    f32x4 z4 = {0.0f, 0.0f, 0.0f, 0.0f};
    int ls = 0;
    int cnt = 0;          // unmasked steps since last rescale (wave-uniform)
    float sc_acc = 0.0f;  // wave3: scores accumulator

    // ---- producer body as a lambda: fills exf[buf]/pbb[buf] for chunk ch ----
    auto produce = [&](int ch, int buf) {
        const int t0c = s * seglen + ch * 64;
        const size_t rowbase = ((size_t)b * TT + t0c + lane) * KK;
        const float4* yp4 = (const float4*)(y_pred + rowbase);
        const float4* yt4 = (const float4*)(y_true + rowbase);
        float dot = 0.0f, labf = 0.0f, pmin = 1e30f;
        float4* exrow = &exf[buf][lane * 13];
#pragma unroll 4
        for (int g = 0; g < 12; g++) {
            float4 p = yp4[g];
            float4 a = yt4[g];
            dot = fmaf(a.x, p.x, fmaf(a.y, p.y, fmaf(a.z, p.z, fmaf(a.w, p.w, dot))));
            float e0 = (float)(4 * g);
            labf = fmaf(a.x, e0, fmaf(a.y, e0 + 1.0f, fmaf(a.z, e0 + 2.0f, fmaf(a.w, e0 + 3.0f, labf))));
            pmin = fminf(pmin, fminf(fminf(p.x, p.y), fminf(p.z, p.w)));
            exrow[g] = make_float4(fexp(p.x), fexp(p.y), fexp(p.z), fexp(p.w));
        }
        bool mt_ok = pmin > -1e6f;
        unsigned long long bal = __ballot(mt_ok);
        if (lane == 0) pbb[buf] = bal;

        // boundary row t0c+64 (label+mask), lanes 0..11 partials
        float labB = 0.0f, pmB = 1e30f;
        const bool hasB = (t0c + 64 < TT);
        if (hasB && lane < 12) {
            const size_t bdbase = ((size_t)b * TT + t0c + 64) * KK;
            float4 a = ((const float4*)(y_true + bdbase))[lane];
            float4 p = ((const float4*)(y_pred + bdbase))[lane];
            float e0 = (float)(4 * lane);
            labB = fmaf(a.x, e0, fmaf(a.y, e0 + 1.0f, fmaf(a.z, e0 + 2.0f, a.w * (e0 + 3.0f))));
            pmB = fminf(fminf(p.x, p.y), fminf(p.z, p.w));
        }
#pragma unroll
        for (int off = 1; off < 16; off <<= 1) {
            labB += __shfl_xor(labB, off);
            pmB = fminf(pmB, __shfl_xor(pmB, off));
        }
        int labB_i = (int)(rdlanef(labB, 0) + 0.5f);
        float mB = (hasB && rdlanef(pmB, 0) > -1e6f) ? 1.0f : 0.0f;

        int labt = (int)(labf + 0.5f);
        float mft = mt_ok ? 1.0f : 0.0f;
        int lnx = __shfl(labt, (lane + 1) & 63);
        float mnx = __shfl(mft, (lane + 1) & 63);
        if (lane == 63) { lnx = labB_i; mnx = mB; }
        sc_acc += mft * dot + mft * mnx * trans[labt * KK + lnx];
    };

    // prologue: producer fills buffer 0 for chunk 0
    if (w == 3) produce(0, 0);
    __syncthreads();

    for (int ch = 0; ch < nch; ch++) {
        const int cur = ch & 1;
        if (w == 3) {
            if (ch + 1 < nch) produce(ch + 1, cur ^ 1);   // overlap with chain(ch)
        } else {
            const unsigned long long mk = pbb[cur];
            const int tt0 = (s == 0 && ch == 0) ? 1 : 0;
            for (int tt = tt0; tt < 64; tt++) {
                if (!((mk >> tt) & 1ull)) continue;

                bf16x8 bf0 = __builtin_bit_cast(bf16x8, *(const uint4*)bptr0);
                bf16x8 bf1 = __builtin_bit_cast(bf16x8, *(const uint4*)bptr1);

                f32x4 acc0 = __builtin_amdgcn_mfma_f32_16x16x32_bf16(afrag[0][0], bf0, z4, 0, 0, 0);
                acc0 = __builtin_amdgcn_mfma_f32_16x16x32_bf16(afrag[0][1], bf1, acc0, 0, 0, 0);
                f32x4 acc1 = __builtin_amdgcn_mfma_f32_16x16x32_bf16(afrag[1][0], bf0, z4, 0, 0, 0);
                acc1 = __builtin_amdgcn_mfma_f32_16x16x32_bf16(afrag[1][1], bf1, acc1, 0, 0, 0);
                f32x4 acc2 = __builtin_amdgcn_mfma_f32_16x16x32_bf16(afrag[2][0], bf0, z4, 0, 0, 0);
                acc2 = __builtin_amdgcn_mfma_f32_16x16x32_bf16(afrag[2][1], bf1, acc2, 0, 0, 0);

                // deferred pow2 rescale: every 6 unmasked steps (overflow-safe;
                // per-step growth < 2^13, 6 steps < 2^78 << fp32/bf16 max 2^127).
                // Fast/slow duplicated tails; slow path pre-scales ex by r (pow2,
                // exact) — bit-identical to original operation order.
                if (++cnt >= 6) {
                    float v00 = rdlanef(acc0[0], 0);
                    int k = (int)(__float_as_uint(v00) >> 23) - 127;
                    float r = __uint_as_float((unsigned int)(127 - k) << 23);
                    ls += k;
                    cnt = 0;
                    float4 ex0 = exf[cur][tt * 13 + q];
                    ex0.x *= r; ex0.y *= r; ex0.z *= r; ex0.w *= r;
                    *(uint2*)wp0 = make_uint2(pktrunc(acc0[0] * ex0.x, acc0[1] * ex0.y),
                                              pktrunc(acc0[2] * ex0.z, acc0[3] * ex0.w));
                    float4 ex1 = exf[cur][tt * 13 + 4 + q];
                    ex1.x *= r; ex1.y *= r; ex1.z *= r; ex1.w *= r;
                    *(uint2*)wp1 = make_uint2(pktrunc(acc1[0] * ex1.x, acc1[1] * ex1.y),
                                              pktrunc(acc1[2] * ex1.z, acc1[3] * ex1.w));
                    float4 ex2 = exf[cur][tt * 13 + 8 + q];
                    ex2.x *= r; ex2.y *= r; ex2.z *= r; ex2.w *= r;
                    *(uint2*)wp2 = make_uint2(pktrunc(acc2[0] * ex2.x, acc2[1] * ex2.y),
                                              pktrunc(acc2[2] * ex2.z, acc2[3] * ex2.w));
                } else {
                    float4 ex0 = exf[cur][tt * 13 + q];
                    *(uint2*)wp0 = make_uint2(pktrunc(acc0[0] * ex0.x, acc0[1] * ex0.y),
                                              pktrunc(acc0[2] * ex0.z, acc0[3] * ex0.w));
                    float4 ex1 = exf[cur][tt * 13 + 4 + q];
                    *(uint2*)wp1 = make_uint2(pktrunc(acc1[0] * ex1.x, acc1[1] * ex1.y),
                                              pktrunc(acc1[2] * ex1.z, acc1[3] * ex1.w));
                    float4 ex2 = exf[cur][tt * 13 + 8 + q];
                    *(uint2*)wp2 = make_uint2(pktrunc(acc2[0] * ex2.x, acc2[1] * ex2.y),
                                              pktrunc(acc2[2] * ex2.z, acc2[3] * ex2.w));
                }
            }
        }
        __syncthreads();    // exf[cur^1] published; chain done with exf[cur]
    }

    // wave3: per-block scores partial (no atomic; every slot written)
    if (w == 3) {
#pragma unroll
        for (int off = 32; off; off >>= 1) sc_acc += __shfl_xor(sc_acc, off);
        if (lane == 0) ws_target[b * nseg + s] = sc_acc;
    }

    // reconcile per-wave pow2 scales (exact), write compact 48x48 bf16 block
    if (w < 3 && lane == 0) lsb[w] = ls;
    __syncthreads();
    if (w < 3 && lane < KK) {
        const int dl = ls - lsb[0];
        bf16_t* Uo = ws_u + (size_t)(b * nseg + s) * SEGELEMS;
        unsigned int wd[8];
#pragma unroll
        for (int j = 0; j < 8; j++) {
            float f0 = ldexpf(bf2f(Ubuf[(16 * w + 2 * j) * UST + lane]), dl);
            float f1 = ldexpf(bf2f(Ubuf[(16 * w + 2 * j + 1) * UST + lane]), dl);
            wd[j] = bf16bits(f0) | (bf16bits(f1) << 16);
        }
        *(uint4*)(Uo + (size_t)lane * 48 + 16 * w) = make_uint4(wd[0], wd[1], wd[2], wd[3]);
        *(uint4*)(Uo + (size_t)lane * 48 + 16 * w + 8) = make_uint4(wd[4], wd[5], wd[6], wd[7]);
    }
    if (tid == 0) ws_ls[b * nseg + s] = lsb[0];
}

// 48x48 product: D = A (global row-major 48x48) x W (LDS col-major stride PST), in place.
// Returns pow2 scale exponent removed. No barriers inside (single-wave safe).
__device__ __forceinline__ int chain_product(const bf16_t* __restrict__ A, bf16_t* Ub, int lane) {
    const int half = lane >> 5;
    const int l31 = lane & 31;
    f32x16 z16;
#pragma unroll
    for (int r = 0; r < 16; r++) z16[r] = 0.0f;

    bf16x8 af[2][3];
#pragma unroll
    for (int mt = 0; mt < 2; mt++) {
        int m = l31 + 32 * mt;
#pragma unroll
        for (int ks = 0; ks < 3; ks++) {
            if (m < KK)
                af[mt][ks] = __builtin_bit_cast(bf16x8, *(const uint4*)&A[(size_t)m * 48 + 16 * ks + 8 * half]);
            else
                af[mt][ks] = __builtin_bit_cast(bf16x8, make_uint4(0, 0, 0, 0));
        }
    }
    bf16x8 bg[3][2];
#pragma unroll
    for (int ks = 0; ks < 3; ks++)
#pragma unroll
        for (int nt = 0; nt < 2; nt++)
            bg[ks][nt] = __builtin_bit_cast(bf16x8, *(const uint4*)&Ub[(l31 + 32 * nt) * PST + 16 * ks + 8 * half]);

    f32x16 acc[4];
#pragma unroll
    for (int mt = 0; mt < 2; mt++)
#pragma unroll
        for (int nt = 0; nt < 2; nt++) {
            f32x16 a0 = __builtin_amdgcn_mfma_f32_32x32x16_bf16(af[mt][0], bg[0][nt], z16, 0, 0, 0);
            a0 = __builtin_amdgcn_mfma_f32_32x32x16_bf16(af[mt][1], bg[1][nt], a0, 0, 0, 0);
            acc[mt * 2 + nt] = __builtin_amdgcn_mfma_f32_32x32x16_bf16(af[mt][2], bg[2][nt], a0, 0, 0, 0);
        }

    float v00 = rdlanef(acc[0][0], 0);
    int k = (int)(__float_as_uint(v00) >> 23) - 127;
    float r = __uint_as_float((unsigned int)(127 - k) << 23);

#pragma unroll
    for (int mt = 0; mt < 2; mt++)
#pragma unroll
        for (int nt = 0; nt < 2; nt++) {
            int c = l31 + 32 * nt;
#pragma unroll
            for (int g = 0; g < 4; g++) {
                int a0 = 32 * mt + 8 * g + 4 * half;
                if (a0 < KK) {
                    const f32x16& Aq = acc[mt * 2 + nt];
                    unsigned int u0 = bf16bits(Aq[4 * g + 0] * r) | (bf16bits(Aq[4 * g + 1] * r) << 16);
                    unsigned int u1 = bf16bits(Aq[4 * g + 2] * r) | (bf16bits(Aq[4 * g + 3] * r) << 16);
                    *(uint2*)&Ub[c * PST + a0] = make_uint2(u0, u1);
                }
            }
        }
    return k;
}

// Variant: A read from LDS col-major slot (A[m][k] = As[k*PST + m]).
__device__ __forceinline__ int chain_product_ldsA(const bf16_t* As, bf16_t* Ub, int lane) {
    const int half = lane >> 5;
    const int l31 = lane & 31;
    f32x16 z16;
#pragma unroll
    for (int r = 0; r < 16; r++) z16[r] = 0.0f;

    bf16x8 af[2][3];
#pragma unroll
    for (int mt = 0; mt < 2; mt++) {
        int m = l31 + 32 * mt;
#pragma unroll
        for (int ks = 0; ks < 3; ks++) {
            bf16x8 f;
#pragma unroll
            for (int j = 0; j < 8; j++) {
                int k = 16 * ks + 8 * half + j;
                f[j] = (m < KK) ? As[k * PST + m] : (bf16_t)0.0f;
            }
            af[mt][ks] = f;
        }
    }
    bf16x8 bg[3][2];
#pragma unroll
    for (int ks = 0; ks < 3; ks++)
#pragma unroll
        for (int nt = 0; nt < 2; nt++)
            bg[ks][nt] = __builtin_bit_cast(bf16x8, *(const uint4*)&Ub[(l31 + 32 * nt) * PST + 16 * ks + 8 * half]);

    f32x16 acc[4];
#pragma unroll
    for (int mt = 0; mt < 2; mt++)
#pragma unroll
        for (int nt = 0; nt < 2; nt++) {
            f32x16 a0 = __builtin_amdgcn_mfma_f32_32x32x16_bf16(af[mt][0], bg[0][nt], z16, 0, 0, 0);
            a0 = __builtin_amdgcn_mfma_f32_32x32x16_bf16(af[mt][1], bg[1][nt], a0, 0, 0, 0);
            acc[mt * 2 + nt] = __builtin_amdgcn_mfma_f32_32x32x16_bf16(af[mt][2], bg[2][nt], a0, 0, 0, 0);
        }

    float v00 = rdlanef(acc[0][0], 0);
    int k = (int)(__float_as_uint(v00) >> 23) - 127;
    float r = __uint_as_float((unsigned int)(127 - k) << 23);

#pragma unroll
    for (int mt = 0; mt < 2; mt++)
#pragma unroll
        for (int nt = 0; nt < 2; nt++) {
            int c = l31 + 32 * nt;
#pragma unroll
            for (int g = 0; g < 4; g++) {
                int a0 = 32 * mt + 8 * g + 4 * half;
                if (a0 < KK) {
                    const f32x16& Aq = acc[mt * 2 + nt];
                    unsigned int u0 = bf16bits(Aq[4 * g + 0] * r) | (bf16bits(Aq[4 * g + 1] * r) << 16);
                    unsigned int u1 = bf16bits(Aq[4 * g + 2] * r) | (bf16bits(Aq[4 * g + 3] * r) << 16);
                    *(uint2*)&Ub[c * PST + a0] = make_uint2(u0, u1);
                }
            }
        }
    return k;
}

// ============ fold_final: merged fold+final — one launch ==========================
// grid B, 256 threads. Wave w serially folds its nseg/4 consecutive slots into
// Ws[w], then 4->2->1 tree + q0 + output (all verified components).
__global__ __launch_bounds__(256) void fold_final_kernel(
    const float* __restrict__ y_pred, const bf16_t* __restrict__ ws_u,
    const int* __restrict__ ws_ls, const float* __restrict__ ws_target,
    float* __restrict__ out, int nseg) {
    const int b = blockIdx.x;
    const int tid = threadIdx.x;
    const int w = tid >> 6, lane = tid & 63;
    const int per = nseg / 4;              // 4 (nseg=16) or 8 (nseg=32)

    __shared__ __align__(16) bf16_t Ws[4][64 * PST];
    __shared__ int lsp[8];
    if (tid < 8) lsp[tid] = 0;
    __syncthreads();

    {   // wave w: fold slots [base, base+per) serially (later segment on the left)
        const int base = b * nseg + per * w;
        const bf16_t* s0 = ws_u + (size_t)base * SEGELEMS;
        for (int k = 0; k < KK; k++)
            Ws[w][lane * PST + k] = (lane < KK) ? s0[(size_t)k * 48 + lane] : (bf16_t)0.0f;
        int lsk = ws_ls[base];
        for (int j = 1; j < per; j++) {
            lsk += ws_ls[base + j];
            lsk += chain_product(ws_u + (size_t)(base + j) * SEGELEMS, Ws[w], lane);
        }
        if (lane == 0) lsp[w] = lsk;
    }
    __syncthreads();
    int k1 = 0;
    if (w == 0) k1 = chain_product_ldsA(Ws[1], Ws[0], lane);        // Ws0 = W1*W0
    if (w == 2) {                                                    // Ws2 = W3*W2
        int k2 = chain_product_ldsA(Ws[3], Ws[2], lane);
        if (lane == 0) lsp[5] = k2;
    }
    __syncthreads();

    if (w == 0) {
        int k3 = chain_product_ldsA(Ws[2], Ws[0], lane);             // Ws0 = (W3W2)(W1W0)
        float L = (float)(lsp[0] + lsp[1] + lsp[2] + lsp[3] + k1 + lsp[5] + k3);

        // q0 from t=0 row
        float x0 = (lane < KK) ? y_pred[(size_t)b * TT * KK + lane] : 0.0f;
        bool ok0 = (lane >= KK) || (x0 > -1e6f);
        bool m0 = (__ballot(ok0) == ~0ull);
        float xeff = (lane < KK) ? (m0 ? x0 : 0.0f) : 0.0f;
        float c0 = rdlanef(xeff, 0);
        float q0 = (lane < KK) ? fexp(xeff - c0) : 0.0f;

        float p = 0.0f;
        if (lane < KK) {
            for (int c = 0; c < KK; c++) {
                float qc = rdlanef(q0, c);
                p = fmaf(bf2f(Ws[0][c * PST + lane]), qc, p);
            }
        }
#pragma unroll
        for (int off = 32; off; off >>= 1) p += __shfl_xor(p, off);

        // target = sum of per-block partials
        float tg = (lane < nseg) ? ws_target[b * nseg + lane] : 0.0f;
#pragma unroll
        for (int off = 32; off; off >>= 1) tg += __shfl_xor(tg, off);

        if (lane == 0) {
            out[b] = c0 + 0.6931471805599453f * (L + flog2(p)) - tg;
        }
    }
}

extern "C" void kernel_launch(void* const* d_in, const int* in_sizes, int n_in,
                              void* d_out, int out_size, void* d_ws, size_t ws_size,
                              hipStream_t stream) {
    const float* y_true = (const float*)d_in[0];
    const float* y_pred = (const float*)d_in[1];
    const float* trans = (const float*)d_in[2];
    float* out = (float*)d_out;

    // adaptive segment count (never overrun d_ws). Tiers: 16 / 32.
    int nseg = 16;
    if (ws_size >= (size_t)WS_U_OFF + (size_t)BB * 32 * SEGBYTES) nseg = 32;

    float* ws_target = (float*)d_ws;                          // BB*nseg floats (<=16 KB)
    int* ws_ls = (int*)((char*)d_ws + WS_LS_OFF);             // BB*nseg ints  (<=16 KB)
    bf16_t* ws_u = (bf16_t*)((char*)d_ws + WS_U_OFF);

    fused_kernel<<<dim3(nseg, BB), 256, 0, stream>>>(
        y_true, y_pred, trans, ws_target, ws_ls, ws_u, nseg);
    fold_final_kernel<<<BB, 256, 0, stream>>>(y_pred, ws_u, ws_ls, ws_target, out, nseg);
}

// Round 11
// 232.773 us; speedup vs baseline: 1.1433x; 1.0128x over previous
//
#include <hip/hip_runtime.h>

#define BB 64
#define TT 4096
#define KK 48
#define UST 56              // Ubuf col stride (bf16): 112 B. MUST be mult of 8 elems
                            // (16 B): r5's UST=58 misaligned ds_read_b128 -> 3.6x slower.
#define PST 56              // phase LDS col stride (bf16)
#define WS_LS_OFF 16384
#define WS_U_OFF 32768
#define SEGBYTES 4608       // compact: 48 rows x 48 col-stride x bf16
#define SEGELEMS 2304

typedef __bf16 bf16_t;
typedef bf16_t bf16x8 __attribute__((ext_vector_type(8)));
typedef float f32x4 __attribute__((ext_vector_type(4)));
typedef float f32x16 __attribute__((ext_vector_type(16)));

__device__ __forceinline__ float fexp(float x) {   // natural exp
    return __builtin_amdgcn_exp2f(x * 1.4426950408889634f);
}
__device__ __forceinline__ float flog2(float x) { return __builtin_amdgcn_logf(x); }
__device__ __forceinline__ float rdlanef(float v, int l) {
    return __int_as_float(__builtin_amdgcn_readlane(__float_as_int(v), l));
}
__device__ __forceinline__ unsigned int bf16bits(float f) {
    return (unsigned int)__builtin_bit_cast(unsigned short, (bf16_t)f);
}
__device__ __forceinline__ float bf2f(bf16_t h) {
    return __uint_as_float(((unsigned int)__builtin_bit_cast(unsigned short, h)) << 16);
}
// pack two fp32 -> bf16x2 by truncation (1 v_perm_b32); lo in low half
__device__ __forceinline__ unsigned int pktrunc(float lo, float hi) {
    return __builtin_amdgcn_perm(__float_as_uint(hi), __float_as_uint(lo), 0x07060302u);
}

// ============ fused: stage1 (waves 0-2) + ex-staging & scores (wave 3) ============
// r11: recombination of the two best verified pieces. Fused = r6 VERBATIM (256
// threads, (256,4), VGPR 48, single exf buffer, 133 us — fastest measured).
// r10's producer double-buffer REVERTED: it regressed fused 133->141 (occupancy
// 48.5->40.6, VGPR 48->60, LDS 18.9->32.3 KB) because cross-block wave overlap
// at 4 blocks/CU already hides the producer — extra pressure, no gain.
// Chain is LDS-pipe/latency bound; bank arithmetic shows b128/b64 accesses are
// perfectly distributed (8 acc/bank = 1KB/128B floor) — conflict counter counts
// inherent multi-phase, not waste. Occupancy is grid-capped (workspace caps
// nseg=16 -> 1024 blocks = 4/CU).
__global__ __launch_bounds__(256, 4) void fused_kernel(
    const float* __restrict__ y_true, const float* __restrict__ y_pred,
    const float* __restrict__ trans, float* __restrict__ ws_target,
    int* __restrict__ ws_ls, bf16_t* __restrict__ ws_u, int nseg) {
    const int s = blockIdx.x, b = blockIdx.y;
    const int seglen = TT / nseg;
    const int nch = seglen / 64;
    const int tid = threadIdx.x;
    const int w = tid >> 6;
    const int lane = tid & 63;
    const int q = lane >> 4;
    const int n = lane & 15;
    const int ncol = 16 * w + n;

    __shared__ __align__(16) float4 exf[64 * 13];             // fp32 ex, stride 13
    __shared__ __align__(16) bf16_t Ubuf[48 * UST + 16];
    __shared__ unsigned long long pb;
    __shared__ int lsb[4];

    // A fragments (waves 0-2): E^T zero-padded in K. A[m][k]: m=16mt+n, k=32ks+8q+j.
    bf16x8 afrag[3][2];
    if (w < 3) {
#pragma unroll
        for (int mt = 0; mt < 3; mt++) {
#pragma unroll
            for (int ks = 0; ks < 2; ks++) {
                bf16x8 f;
#pragma unroll
                for (int j = 0; j < 8; j++) {
                    int k = 32 * ks + 8 * q + j;
                    float v = (k < KK) ? fexp(trans[k * KK + 16 * mt + n]) : 0.0f;
                    f[j] = (bf16_t)v;
                }
                afrag[mt][ks] = f;
            }
        }
    }

    {   // zero Ubuf then identity diag
        uint4* p = (uint4*)Ubuf;
        for (int i = tid; i < (48 * UST + 16) / 8; i += 256) p[i] = make_uint4(0, 0, 0, 0);
    }
    __syncthreads();
    if (tid < KK) Ubuf[tid * UST + tid] = (bf16_t)1.0f;

    const bf16_t* bptr0 = &Ubuf[ncol * UST + 8 * q];
    const bf16_t* bptr1 = &Ubuf[ncol * UST + 32 + 8 * q];
    bf16_t* wp0 = &Ubuf[ncol * UST + 0 + 4 * q];
    bf16_t* wp1 = &Ubuf[ncol * UST + 16 + 4 * q];
    bf16_t* wp2 = &Ubuf[ncol * UST + 32 + 4 * q];

    f32x4 z4 = {0.0f, 0.0f, 0.0f, 0.0f};
    int ls = 0;
    int cnt = 0;          // unmasked steps since last rescale (wave-uniform)
    float sc_acc = 0.0f;  // wave3: scores accumulator

    for (int ch = 0; ch < nch; ch++) {
        __syncthreads();                     // previous exf fully consumed
        if (w == 3) {
            // ---- producer + scores: lane = local timestep ----
            const int t0c = s * seglen + ch * 64;
            const size_t rowbase = ((size_t)b * TT + t0c + lane) * KK;
            const float4* yp4 = (const float4*)(y_pred + rowbase);
            const float4* yt4 = (const float4*)(y_true + rowbase);
            float dot = 0.0f, labf = 0.0f, pmin = 1e30f;
            float4* exrow = &exf[lane * 13];
#pragma unroll 4
            for (int g = 0; g < 12; g++) {
                float4 p = yp4[g];
                float4 a = yt4[g];
                dot = fmaf(a.x, p.x, fmaf(a.y, p.y, fmaf(a.z, p.z, fmaf(a.w, p.w, dot))));
                float e0 = (float)(4 * g);
                labf = fmaf(a.x, e0, fmaf(a.y, e0 + 1.0f, fmaf(a.z, e0 + 2.0f, fmaf(a.w, e0 + 3.0f, labf))));
                pmin = fminf(pmin, fminf(fminf(p.x, p.y), fminf(p.z, p.w)));
                exrow[g] = make_float4(fexp(p.x), fexp(p.y), fexp(p.z), fexp(p.w));
            }
            bool mt_ok = pmin > -1e6f;
            unsigned long long bal = __ballot(mt_ok);
            if (lane == 0) pb = bal;

            // boundary row t0c+64 (label+mask), lanes 0..11 partials
            float labB = 0.0f, pmB = 1e30f;
            const bool hasB = (t0c + 64 < TT);
            if (hasB && lane < 12) {
                const size_t bdbase = ((size_t)b * TT + t0c + 64) * KK;
                float4 a = ((const float4*)(y_true + bdbase))[lane];
                float4 p = ((const float4*)(y_pred + bdbase))[lane];
                float e0 = (float)(4 * lane);
                labB = fmaf(a.x, e0, fmaf(a.y, e0 + 1.0f, fmaf(a.z, e0 + 2.0f, a.w * (e0 + 3.0f))));
                pmB = fminf(fminf(p.x, p.y), fminf(p.z, p.w));
            }
#pragma unroll
            for (int off = 1; off < 16; off <<= 1) {
                labB += __shfl_xor(labB, off);
                pmB = fminf(pmB, __shfl_xor(pmB, off));
            }
            int labB_i = (int)(rdlanef(labB, 0) + 0.5f);
            float mB = (hasB && rdlanef(pmB, 0) > -1e6f) ? 1.0f : 0.0f;

            int labt = (int)(labf + 0.5f);
            float mft = mt_ok ? 1.0f : 0.0f;
            int lnx = __shfl(labt, (lane + 1) & 63);
            float mnx = __shfl(mft, (lane + 1) & 63);
            if (lane == 63) { lnx = labB_i; mnx = mB; }
            sc_acc += mft * dot + mft * mnx * trans[labt * KK + lnx];
        }
        __syncthreads();
        if (w < 3) {
            const unsigned long long mk = pb;
            const int tt0 = (s == 0 && ch == 0) ? 1 : 0;
            for (int tt = tt0; tt < 64; tt++) {
                if (!((mk >> tt) & 1ull)) continue;

                bf16x8 bf0 = __builtin_bit_cast(bf16x8, *(const uint4*)bptr0);
                bf16x8 bf1 = __builtin_bit_cast(bf16x8, *(const uint4*)bptr1);

                f32x4 acc0 = __builtin_amdgcn_mfma_f32_16x16x32_bf16(afrag[0][0], bf0, z4, 0, 0, 0);
                acc0 = __builtin_amdgcn_mfma_f32_16x16x32_bf16(afrag[0][1], bf1, acc0, 0, 0, 0);
                f32x4 acc1 = __builtin_amdgcn_mfma_f32_16x16x32_bf16(afrag[1][0], bf0, z4, 0, 0, 0);
                acc1 = __builtin_amdgcn_mfma_f32_16x16x32_bf16(afrag[1][1], bf1, acc1, 0, 0, 0);
                f32x4 acc2 = __builtin_amdgcn_mfma_f32_16x16x32_bf16(afrag[2][0], bf0, z4, 0, 0, 0);
                acc2 = __builtin_amdgcn_mfma_f32_16x16x32_bf16(afrag[2][1], bf1, acc2, 0, 0, 0);

                // deferred pow2 rescale: every 6 unmasked steps (overflow-safe;
                // per-step growth < 2^13, 6 steps < 2^78 << fp32/bf16 max 2^127).
                // Fast/slow duplicated tails; slow path pre-scales ex by r (pow2,
                // exact) — bit-identical to original operation order.
                if (++cnt >= 6) {
                    float v00 = rdlanef(acc0[0], 0);
                    int k = (int)(__float_as_uint(v00) >> 23) - 127;
                    float r = __uint_as_float((unsigned int)(127 - k) << 23);
                    ls += k;
                    cnt = 0;
                    float4 ex0 = exf[tt * 13 + q];
                    ex0.x *= r; ex0.y *= r; ex0.z *= r; ex0.w *= r;
                    *(uint2*)wp0 = make_uint2(pktrunc(acc0[0] * ex0.x, acc0[1] * ex0.y),
                                              pktrunc(acc0[2] * ex0.z, acc0[3] * ex0.w));
                    float4 ex1 = exf[tt * 13 + 4 + q];
                    ex1.x *= r; ex1.y *= r; ex1.z *= r; ex1.w *= r;
                    *(uint2*)wp1 = make_uint2(pktrunc(acc1[0] * ex1.x, acc1[1] * ex1.y),
                                              pktrunc(acc1[2] * ex1.z, acc1[3] * ex1.w));
                    float4 ex2 = exf[tt * 13 + 8 + q];
                    ex2.x *= r; ex2.y *= r; ex2.z *= r; ex2.w *= r;
                    *(uint2*)wp2 = make_uint2(pktrunc(acc2[0] * ex2.x, acc2[1] * ex2.y),
                                              pktrunc(acc2[2] * ex2.z, acc2[3] * ex2.w));
                } else {
                    float4 ex0 = exf[tt * 13 + q];
                    *(uint2*)wp0 = make_uint2(pktrunc(acc0[0] * ex0.x, acc0[1] * ex0.y),
                                              pktrunc(acc0[2] * ex0.z, acc0[3] * ex0.w));
                    float4 ex1 = exf[tt * 13 + 4 + q];
                    *(uint2*)wp1 = make_uint2(pktrunc(acc1[0] * ex1.x, acc1[1] * ex1.y),
                                              pktrunc(acc1[2] * ex1.z, acc1[3] * ex1.w));
                    float4 ex2 = exf[tt * 13 + 8 + q];
                    *(uint2*)wp2 = make_uint2(pktrunc(acc2[0] * ex2.x, acc2[1] * ex2.y),
                                              pktrunc(acc2[2] * ex2.z, acc2[3] * ex2.w));
                }
            }
        }
    }

    // wave3: per-block scores partial (no atomic; every slot written)
    if (w == 3) {
#pragma unroll
        for (int off = 32; off; off >>= 1) sc_acc += __shfl_xor(sc_acc, off);
        if (lane == 0) ws_target[b * nseg + s] = sc_acc;
    }

    // reconcile per-wave pow2 scales (exact), write compact 48x48 bf16 block
    if (w < 3 && lane == 0) lsb[w] = ls;
    __syncthreads();
    if (w < 3 && lane < KK) {
        const int dl = ls - lsb[0];
        bf16_t* Uo = ws_u + (size_t)(b * nseg + s) * SEGELEMS;
        unsigned int wd[8];
#pragma unroll
        for (int j = 0; j < 8; j++) {
            float f0 = ldexpf(bf2f(Ubuf[(16 * w + 2 * j) * UST + lane]), dl);
            float f1 = ldexpf(bf2f(Ubuf[(16 * w + 2 * j + 1) * UST + lane]), dl);
            wd[j] = bf16bits(f0) | (bf16bits(f1) << 16);
        }
        *(uint4*)(Uo + (size_t)lane * 48 + 16 * w) = make_uint4(wd[0], wd[1], wd[2], wd[3]);
        *(uint4*)(Uo + (size_t)lane * 48 + 16 * w + 8) = make_uint4(wd[4], wd[5], wd[6], wd[7]);
    }
    if (tid == 0) ws_ls[b * nseg + s] = lsb[0];
}

// 48x48 product: D = A (global row-major 48x48) x W (LDS col-major stride PST), in place.
// Returns pow2 scale exponent removed. No barriers inside (single-wave safe).
__device__ __forceinline__ int chain_product(const bf16_t* __restrict__ A, bf16_t* Ub, int lane) {
    const int half = lane >> 5;
    const int l31 = lane & 31;
    f32x16 z16;
#pragma unroll
    for (int r = 0; r < 16; r++) z16[r] = 0.0f;

    bf16x8 af[2][3];
#pragma unroll
    for (int mt = 0; mt < 2; mt++) {
        int m = l31 + 32 * mt;
#pragma unroll
        for (int ks = 0; ks < 3; ks++) {
            if (m < KK)
                af[mt][ks] = __builtin_bit_cast(bf16x8, *(const uint4*)&A[(size_t)m * 48 + 16 * ks + 8 * half]);
            else
                af[mt][ks] = __builtin_bit_cast(bf16x8, make_uint4(0, 0, 0, 0));
        }
    }
    bf16x8 bg[3][2];
#pragma unroll
    for (int ks = 0; ks < 3; ks++)
#pragma unroll
        for (int nt = 0; nt < 2; nt++)
            bg[ks][nt] = __builtin_bit_cast(bf16x8, *(const uint4*)&Ub[(l31 + 32 * nt) * PST + 16 * ks + 8 * half]);

    f32x16 acc[4];
#pragma unroll
    for (int mt = 0; mt < 2; mt++)
#pragma unroll
        for (int nt = 0; nt < 2; nt++) {
            f32x16 a0 = __builtin_amdgcn_mfma_f32_32x32x16_bf16(af[mt][0], bg[0][nt], z16, 0, 0, 0);
            a0 = __builtin_amdgcn_mfma_f32_32x32x16_bf16(af[mt][1], bg[1][nt], a0, 0, 0, 0);
            acc[mt * 2 + nt] = __builtin_amdgcn_mfma_f32_32x32x16_bf16(af[mt][2], bg[2][nt], a0, 0, 0, 0);
        }

    float v00 = rdlanef(acc[0][0], 0);
    int k = (int)(__float_as_uint(v00) >> 23) - 127;
    float r = __uint_as_float((unsigned int)(127 - k) << 23);

#pragma unroll
    for (int mt = 0; mt < 2; mt++)
#pragma unroll
        for (int nt = 0; nt < 2; nt++) {
            int c = l31 + 32 * nt;
#pragma unroll
            for (int g = 0; g < 4; g++) {
                int a0 = 32 * mt + 8 * g + 4 * half;
                if (a0 < KK) {
                    const f32x16& Aq = acc[mt * 2 + nt];
                    unsigned int u0 = bf16bits(Aq[4 * g + 0] * r) | (bf16bits(Aq[4 * g + 1] * r) << 16);
                    unsigned int u1 = bf16bits(Aq[4 * g + 2] * r) | (bf16bits(Aq[4 * g + 3] * r) << 16);
                    *(uint2*)&Ub[c * PST + a0] = make_uint2(u0, u1);
                }
            }
        }
    return k;
}

// Variant: A read from LDS col-major slot (A[m][k] = As[k*PST + m]).
__device__ __forceinline__ int chain_product_ldsA(const bf16_t* As, bf16_t* Ub, int lane) {
    const int half = lane >> 5;
    const int l31 = lane & 31;
    f32x16 z16;
#pragma unroll
    for (int r = 0; r < 16; r++) z16[r] = 0.0f;

    bf16x8 af[2][3];
#pragma unroll
    for (int mt = 0; mt < 2; mt++) {
        int m = l31 + 32 * mt;
#pragma unroll
        for (int ks = 0; ks < 3; ks++) {
            bf16x8 f;
#pragma unroll
            for (int j = 0; j < 8; j++) {
                int k = 16 * ks + 8 * half + j;
                f[j] = (m < KK) ? As[k * PST + m] : (bf16_t)0.0f;
            }
            af[mt][ks] = f;
        }
    }
    bf16x8 bg[3][2];
#pragma unroll
    for (int ks = 0; ks < 3; ks++)
#pragma unroll
        for (int nt = 0; nt < 2; nt++)
            bg[ks][nt] = __builtin_bit_cast(bf16x8, *(const uint4*)&Ub[(l31 + 32 * nt) * PST + 16 * ks + 8 * half]);

    f32x16 acc[4];
#pragma unroll
    for (int mt = 0; mt < 2; mt++)
#pragma unroll
        for (int nt = 0; nt < 2; nt++) {
            f32x16 a0 = __builtin_amdgcn_mfma_f32_32x32x16_bf16(af[mt][0], bg[0][nt], z16, 0, 0, 0);
            a0 = __builtin_amdgcn_mfma_f32_32x32x16_bf16(af[mt][1], bg[1][nt], a0, 0, 0, 0);
            acc[mt * 2 + nt] = __builtin_amdgcn_mfma_f32_32x32x16_bf16(af[mt][2], bg[2][nt], a0, 0, 0, 0);
        }

    float v00 = rdlanef(acc[0][0], 0);
    int k = (int)(__float_as_uint(v00) >> 23) - 127;
    float r = __uint_as_float((unsigned int)(127 - k) << 23);

#pragma unroll
    for (int mt = 0; mt < 2; mt++)
#pragma unroll
        for (int nt = 0; nt < 2; nt++) {
            int c = l31 + 32 * nt;
#pragma unroll
            for (int g = 0; g < 4; g++) {
                int a0 = 32 * mt + 8 * g + 4 * half;
                if (a0 < KK) {
                    const f32x16& Aq = acc[mt * 2 + nt];
                    unsigned int u0 = bf16bits(Aq[4 * g + 0] * r) | (bf16bits(Aq[4 * g + 1] * r) << 16);
                    unsigned int u1 = bf16bits(Aq[4 * g + 2] * r) | (bf16bits(Aq[4 * g + 3] * r) << 16);
                    *(uint2*)&Ub[c * PST + a0] = make_uint2(u0, u1);
                }
            }
        }
    return k;
}

// ============ fold_final: merged fold+final — one launch ==========================
// grid B, 256 threads. Wave w serially folds its nseg/4 consecutive slots into
// Ws[w], then 4->2->1 tree + q0 + output (all verified components; r9/r10 passed).
__global__ __launch_bounds__(256) void fold_final_kernel(
    const float* __restrict__ y_pred, const bf16_t* __restrict__ ws_u,
    const int* __restrict__ ws_ls, const float* __restrict__ ws_target,
    float* __restrict__ out, int nseg) {
    const int b = blockIdx.x;
    const int tid = threadIdx.x;
    const int w = tid >> 6, lane = tid & 63;
    const int per = nseg / 4;              // 4 (nseg=16) or 8 (nseg=32)

    __shared__ __align__(16) bf16_t Ws[4][64 * PST];
    __shared__ int lsp[8];
    if (tid < 8) lsp[tid] = 0;
    __syncthreads();

    {   // wave w: fold slots [base, base+per) serially (later segment on the left)
        const int base = b * nseg + per * w;
        const bf16_t* s0 = ws_u + (size_t)base * SEGELEMS;
        for (int k = 0; k < KK; k++)
            Ws[w][lane * PST + k] = (lane < KK) ? s0[(size_t)k * 48 + lane] : (bf16_t)0.0f;
        int lsk = ws_ls[base];
        for (int j = 1; j < per; j++) {
            lsk += ws_ls[base + j];
            lsk += chain_product(ws_u + (size_t)(base + j) * SEGELEMS, Ws[w], lane);
        }
        if (lane == 0) lsp[w] = lsk;
    }
    __syncthreads();
    int k1 = 0;
    if (w == 0) k1 = chain_product_ldsA(Ws[1], Ws[0], lane);        // Ws0 = W1*W0
    if (w == 2) {                                                    // Ws2 = W3*W2
        int k2 = chain_product_ldsA(Ws[3], Ws[2], lane);
        if (lane == 0) lsp[5] = k2;
    }
    __syncthreads();

    if (w == 0) {
        int k3 = chain_product_ldsA(Ws[2], Ws[0], lane);             // Ws0 = (W3W2)(W1W0)
        float L = (float)(lsp[0] + lsp[1] + lsp[2] + lsp[3] + k1 + lsp[5] + k3);

        // q0 from t=0 row
        float x0 = (lane < KK) ? y_pred[(size_t)b * TT * KK + lane] : 0.0f;
        bool ok0 = (lane >= KK) || (x0 > -1e6f);
        bool m0 = (__ballot(ok0) == ~0ull);
        float xeff = (lane < KK) ? (m0 ? x0 : 0.0f) : 0.0f;
        float c0 = rdlanef(xeff, 0);
        float q0 = (lane < KK) ? fexp(xeff - c0) : 0.0f;

        float p = 0.0f;
        if (lane < KK) {
            for (int c = 0; c < KK; c++) {
                float qc = rdlanef(q0, c);
                p = fmaf(bf2f(Ws[0][c * PST + lane]), qc, p);
            }
        }
#pragma unroll
        for (int off = 32; off; off >>= 1) p += __shfl_xor(p, off);

        // target = sum of per-block partials
        float tg = (lane < nseg) ? ws_target[b * nseg + lane] : 0.0f;
#pragma unroll
        for (int off = 32; off; off >>= 1) tg += __shfl_xor(tg, off);

        if (lane == 0) {
            out[b] = c0 + 0.6931471805599453f * (L + flog2(p)) - tg;
        }
    }
}

extern "C" void kernel_launch(void* const* d_in, const int* in_sizes, int n_in,
                              void* d_out, int out_size, void* d_ws, size_t ws_size,
                              hipStream_t stream) {
    const float* y_true = (const float*)d_in[0];
    const float* y_pred = (const float*)d_in[1];
    const float* trans = (const float*)d_in[2];
    float* out = (float*)d_out;

    // adaptive segment count (never overrun d_ws). Tiers: 16 / 32.
    int nseg = 16;
    if (ws_size >= (size_t)WS_U_OFF + (size_t)BB * 32 * SEGBYTES) nseg = 32;

    float* ws_target = (float*)d_ws;                          // BB*nseg floats (<=16 KB)
    int* ws_ls = (int*)((char*)d_ws + WS_LS_OFF);             // BB*nseg ints  (<=16 KB)
    bf16_t* ws_u = (bf16_t*)((char*)d_ws + WS_U_OFF);

    fused_kernel<<<dim3(nseg, BB), 256, 0, stream>>>(
        y_true, y_pred, trans, ws_target, ws_ls, ws_u, nseg);
    fold_final_kernel<<<BB, 256, 0, stream>>>(y_pred, ws_u, ws_ls, ws_target, out, nseg);
}

// Round 12
// 230.694 us; speedup vs baseline: 1.1536x; 1.0090x over previous
//
#include <hip/hip_runtime.h>

#define BB 64
#define TT 4096
#define KK 48
#define UST 56              // Ubuf col stride (bf16): 112 B. MUST be mult of 8 elems
                            // (16 B): r5's UST=58 misaligned ds_read_b128 -> 3.6x slower.
#define PST 56              // phase LDS col stride (bf16)
#define WS_LS_OFF 16384
#define WS_U_OFF 32768
#define SEGBYTES 4608       // compact: 48 rows x 48 col-stride x bf16
#define SEGELEMS 2304

typedef __bf16 bf16_t;
typedef bf16_t bf16x8 __attribute__((ext_vector_type(8)));
typedef float f32x4 __attribute__((ext_vector_type(4)));
typedef float f32x16 __attribute__((ext_vector_type(16)));

__device__ __forceinline__ float fexp(float x) {   // natural exp
    return __builtin_amdgcn_exp2f(x * 1.4426950408889634f);
}
__device__ __forceinline__ float flog2(float x) { return __builtin_amdgcn_logf(x); }
__device__ __forceinline__ float rdlanef(float v, int l) {
    return __int_as_float(__builtin_amdgcn_readlane(__float_as_int(v), l));
}
__device__ __forceinline__ unsigned int bf16bits(float f) {
    return (unsigned int)__builtin_bit_cast(unsigned short, (bf16_t)f);
}
__device__ __forceinline__ float bf2f(bf16_t h) {
    return __uint_as_float(((unsigned int)__builtin_bit_cast(unsigned short, h)) << 16);
}
// pack two fp32 -> bf16x2 by truncation (1 v_perm_b32); lo in low half
__device__ __forceinline__ unsigned int pktrunc(float lo, float hi) {
    return __builtin_amdgcn_perm(__float_as_uint(hi), __float_as_uint(lo), 0x07060302u);
}

// ============ fused: stage1 (waves 0-2) + ex-staging & scores (wave 3) ============
// r12: MIXED-LENGTH segments unlock nseg beyond 16 within the known workspace
// window [6.32, 9.47) MB. Segments need only be multiples of 128 summing to 4096:
// a=32-nseg segs of 256 + (2*nseg-32) of 128. nseg=20 needs 5.93MB (GUARANTEED),
// 24 -> 7.11MB, 28 -> 8.29MB. Grid 1024 -> >=1280 blocks; resident 4 -> 5
// blocks/CU (VGPR 48 allows 5 waves/EU); surplus blocks queue, so short blocks
// drain and backfill behind the 256-step ones (load balance). Chain code is r6/r11
// VERBATIM — only len/start become per-block functions of s.
__global__ __launch_bounds__(256, 4) void fused_kernel(
    const float* __restrict__ y_true, const float* __restrict__ y_pred,
    const float* __restrict__ trans, float* __restrict__ ws_target,
    int* __restrict__ ws_ls, bf16_t* __restrict__ ws_u, int nseg) {
    const int s = blockIdx.x, b = blockIdx.y;
    const int nlong = 32 - nseg;            // count of 256-len segments (rest 128)
    const int lenv = (s < nlong) ? 256 : 128;
    const int nch = lenv / 64;
    const int segstart = (s < nlong) ? 256 * s : 256 * nlong + 128 * (s - nlong);
    const int tid = threadIdx.x;
    const int w = tid >> 6;
    const int lane = tid & 63;
    const int q = lane >> 4;
    const int n = lane & 15;
    const int ncol = 16 * w + n;

    __shared__ __align__(16) float4 exf[64 * 13];             // fp32 ex, stride 13
    __shared__ __align__(16) bf16_t Ubuf[48 * UST + 16];
    __shared__ unsigned long long pb;
    __shared__ int lsb[4];

    // A fragments (waves 0-2): E^T zero-padded in K. A[m][k]: m=16mt+n, k=32ks+8q+j.
    bf16x8 afrag[3][2];
    if (w < 3) {
#pragma unroll
        for (int mt = 0; mt < 3; mt++) {
#pragma unroll
            for (int ks = 0; ks < 2; ks++) {
                bf16x8 f;
#pragma unroll
                for (int j = 0; j < 8; j++) {
                    int k = 32 * ks + 8 * q + j;
                    float v = (k < KK) ? fexp(trans[k * KK + 16 * mt + n]) : 0.0f;
                    f[j] = (bf16_t)v;
                }
                afrag[mt][ks] = f;
            }
        }
    }

    {   // zero Ubuf then identity diag
        uint4* p = (uint4*)Ubuf;
        for (int i = tid; i < (48 * UST + 16) / 8; i += 256) p[i] = make_uint4(0, 0, 0, 0);
    }
    __syncthreads();
    if (tid < KK) Ubuf[tid * UST + tid] = (bf16_t)1.0f;

    const bf16_t* bptr0 = &Ubuf[ncol * UST + 8 * q];
    const bf16_t* bptr1 = &Ubuf[ncol * UST + 32 + 8 * q];
    bf16_t* wp0 = &Ubuf[ncol * UST + 0 + 4 * q];
    bf16_t* wp1 = &Ubuf[ncol * UST + 16 + 4 * q];
    bf16_t* wp2 = &Ubuf[ncol * UST + 32 + 4 * q];

    f32x4 z4 = {0.0f, 0.0f, 0.0f, 0.0f};
    int ls = 0;
    int cnt = 0;          // unmasked steps since last rescale (wave-uniform)
    float sc_acc = 0.0f;  // wave3: scores accumulator

    for (int ch = 0; ch < nch; ch++) {
        __syncthreads();                     // previous exf fully consumed
        if (w == 3) {
            // ---- producer + scores: lane = local timestep ----
            const int t0c = segstart + ch * 64;
            const size_t rowbase = ((size_t)b * TT + t0c + lane) * KK;
            const float4* yp4 = (const float4*)(y_pred + rowbase);
            const float4* yt4 = (const float4*)(y_true + rowbase);
            float dot = 0.0f, labf = 0.0f, pmin = 1e30f;
            float4* exrow = &exf[lane * 13];
#pragma unroll 4
            for (int g = 0; g < 12; g++) {
                float4 p = yp4[g];
                float4 a = yt4[g];
                dot = fmaf(a.x, p.x, fmaf(a.y, p.y, fmaf(a.z, p.z, fmaf(a.w, p.w, dot))));
                float e0 = (float)(4 * g);
                labf = fmaf(a.x, e0, fmaf(a.y, e0 + 1.0f, fmaf(a.z, e0 + 2.0f, fmaf(a.w, e0 + 3.0f, labf))));
                pmin = fminf(pmin, fminf(fminf(p.x, p.y), fminf(p.z, p.w)));
                exrow[g] = make_float4(fexp(p.x), fexp(p.y), fexp(p.z), fexp(p.w));
            }
            bool mt_ok = pmin > -1e6f;
            unsigned long long bal = __ballot(mt_ok);
            if (lane == 0) pb = bal;

            // boundary row t0c+64 (label+mask), lanes 0..11 partials
            float labB = 0.0f, pmB = 1e30f;
            const bool hasB = (t0c + 64 < TT);
            if (hasB && lane < 12) {
                const size_t bdbase = ((size_t)b * TT + t0c + 64) * KK;
                float4 a = ((const float4*)(y_true + bdbase))[lane];
                float4 p = ((const float4*)(y_pred + bdbase))[lane];
                float e0 = (float)(4 * lane);
                labB = fmaf(a.x, e0, fmaf(a.y, e0 + 1.0f, fmaf(a.z, e0 + 2.0f, a.w * (e0 + 3.0f))));
                pmB = fminf(fminf(p.x, p.y), fminf(p.z, p.w));
            }
#pragma unroll
            for (int off = 1; off < 16; off <<= 1) {
                labB += __shfl_xor(labB, off);
                pmB = fminf(pmB, __shfl_xor(pmB, off));
            }
            int labB_i = (int)(rdlanef(labB, 0) + 0.5f);
            float mB = (hasB && rdlanef(pmB, 0) > -1e6f) ? 1.0f : 0.0f;

            int labt = (int)(labf + 0.5f);
            float mft = mt_ok ? 1.0f : 0.0f;
            int lnx = __shfl(labt, (lane + 1) & 63);
            float mnx = __shfl(mft, (lane + 1) & 63);
            if (lane == 63) { lnx = labB_i; mnx = mB; }
            sc_acc += mft * dot + mft * mnx * trans[labt * KK + lnx];
        }
        __syncthreads();
        if (w < 3) {
            const unsigned long long mk = pb;
            const int tt0 = (s == 0 && ch == 0) ? 1 : 0;
            for (int tt = tt0; tt < 64; tt++) {
                if (!((mk >> tt) & 1ull)) continue;

                bf16x8 bf0 = __builtin_bit_cast(bf16x8, *(const uint4*)bptr0);
                bf16x8 bf1 = __builtin_bit_cast(bf16x8, *(const uint4*)bptr1);

                f32x4 acc0 = __builtin_amdgcn_mfma_f32_16x16x32_bf16(afrag[0][0], bf0, z4, 0, 0, 0);
                acc0 = __builtin_amdgcn_mfma_f32_16x16x32_bf16(afrag[0][1], bf1, acc0, 0, 0, 0);
                f32x4 acc1 = __builtin_amdgcn_mfma_f32_16x16x32_bf16(afrag[1][0], bf0, z4, 0, 0, 0);
                acc1 = __builtin_amdgcn_mfma_f32_16x16x32_bf16(afrag[1][1], bf1, acc1, 0, 0, 0);
                f32x4 acc2 = __builtin_amdgcn_mfma_f32_16x16x32_bf16(afrag[2][0], bf0, z4, 0, 0, 0);
                acc2 = __builtin_amdgcn_mfma_f32_16x16x32_bf16(afrag[2][1], bf1, acc2, 0, 0, 0);

                // deferred pow2 rescale: every 6 unmasked steps (overflow-safe;
                // per-step growth < 2^13, 6 steps < 2^78 << fp32/bf16 max 2^127).
                // Fast/slow duplicated tails; slow path pre-scales ex by r (pow2,
                // exact) — bit-identical to original operation order.
                if (++cnt >= 6) {
                    float v00 = rdlanef(acc0[0], 0);
                    int k = (int)(__float_as_uint(v00) >> 23) - 127;
                    float r = __uint_as_float((unsigned int)(127 - k) << 23);
                    ls += k;
                    cnt = 0;
                    float4 ex0 = exf[tt * 13 + q];
                    ex0.x *= r; ex0.y *= r; ex0.z *= r; ex0.w *= r;
                    *(uint2*)wp0 = make_uint2(pktrunc(acc0[0] * ex0.x, acc0[1] * ex0.y),
                                              pktrunc(acc0[2] * ex0.z, acc0[3] * ex0.w));
                    float4 ex1 = exf[tt * 13 + 4 + q];
                    ex1.x *= r; ex1.y *= r; ex1.z *= r; ex1.w *= r;
                    *(uint2*)wp1 = make_uint2(pktrunc(acc1[0] * ex1.x, acc1[1] * ex1.y),
                                              pktrunc(acc1[2] * ex1.z, acc1[3] * ex1.w));
                    float4 ex2 = exf[tt * 13 + 8 + q];
                    ex2.x *= r; ex2.y *= r; ex2.z *= r; ex2.w *= r;
                    *(uint2*)wp2 = make_uint2(pktrunc(acc2[0] * ex2.x, acc2[1] * ex2.y),
                                              pktrunc(acc2[2] * ex2.z, acc2[3] * ex2.w));
                } else {
                    float4 ex0 = exf[tt * 13 + q];
                    *(uint2*)wp0 = make_uint2(pktrunc(acc0[0] * ex0.x, acc0[1] * ex0.y),
                                              pktrunc(acc0[2] * ex0.z, acc0[3] * ex0.w));
                    float4 ex1 = exf[tt * 13 + 4 + q];
                    *(uint2*)wp1 = make_uint2(pktrunc(acc1[0] * ex1.x, acc1[1] * ex1.y),
                                              pktrunc(acc1[2] * ex1.z, acc1[3] * ex1.w));
                    float4 ex2 = exf[tt * 13 + 8 + q];
                    *(uint2*)wp2 = make_uint2(pktrunc(acc2[0] * ex2.x, acc2[1] * ex2.y),
                                              pktrunc(acc2[2] * ex2.z, acc2[3] * ex2.w));
                }
            }
        }
    }

    // wave3: per-block scores partial (no atomic; every slot written)
    if (w == 3) {
#pragma unroll
        for (int off = 32; off; off >>= 1) sc_acc += __shfl_xor(sc_acc, off);
        if (lane == 0) ws_target[b * nseg + s] = sc_acc;
    }

    // reconcile per-wave pow2 scales (exact), write compact 48x48 bf16 block
    if (w < 3 && lane == 0) lsb[w] = ls;
    __syncthreads();
    if (w < 3 && lane < KK) {
        const int dl = ls - lsb[0];
        bf16_t* Uo = ws_u + (size_t)(b * nseg + s) * SEGELEMS;
        unsigned int wd[8];
#pragma unroll
        for (int j = 0; j < 8; j++) {
            float f0 = ldexpf(bf2f(Ubuf[(16 * w + 2 * j) * UST + lane]), dl);
            float f1 = ldexpf(bf2f(Ubuf[(16 * w + 2 * j + 1) * UST + lane]), dl);
            wd[j] = bf16bits(f0) | (bf16bits(f1) << 16);
        }
        *(uint4*)(Uo + (size_t)lane * 48 + 16 * w) = make_uint4(wd[0], wd[1], wd[2], wd[3]);
        *(uint4*)(Uo + (size_t)lane * 48 + 16 * w + 8) = make_uint4(wd[4], wd[5], wd[6], wd[7]);
    }
    if (tid == 0) ws_ls[b * nseg + s] = lsb[0];
}

// 48x48 product: D = A (global row-major 48x48) x W (LDS col-major stride PST), in place.
// Returns pow2 scale exponent removed. No barriers inside (single-wave safe).
__device__ __forceinline__ int chain_product(const bf16_t* __restrict__ A, bf16_t* Ub, int lane) {
    const int half = lane >> 5;
    const int l31 = lane & 31;
    f32x16 z16;
#pragma unroll
    for (int r = 0; r < 16; r++) z16[r] = 0.0f;

    bf16x8 af[2][3];
#pragma unroll
    for (int mt = 0; mt < 2; mt++) {
        int m = l31 + 32 * mt;
#pragma unroll
        for (int ks = 0; ks < 3; ks++) {
            if (m < KK)
                af[mt][ks] = __builtin_bit_cast(bf16x8, *(const uint4*)&A[(size_t)m * 48 + 16 * ks + 8 * half]);
            else
                af[mt][ks] = __builtin_bit_cast(bf16x8, make_uint4(0, 0, 0, 0));
        }
    }
    bf16x8 bg[3][2];
#pragma unroll
    for (int ks = 0; ks < 3; ks++)
#pragma unroll
        for (int nt = 0; nt < 2; nt++)
            bg[ks][nt] = __builtin_bit_cast(bf16x8, *(const uint4*)&Ub[(l31 + 32 * nt) * PST + 16 * ks + 8 * half]);

    f32x16 acc[4];
#pragma unroll
    for (int mt = 0; mt < 2; mt++)
#pragma unroll
        for (int nt = 0; nt < 2; nt++) {
            f32x16 a0 = __builtin_amdgcn_mfma_f32_32x32x16_bf16(af[mt][0], bg[0][nt], z16, 0, 0, 0);
            a0 = __builtin_amdgcn_mfma_f32_32x32x16_bf16(af[mt][1], bg[1][nt], a0, 0, 0, 0);
            acc[mt * 2 + nt] = __builtin_amdgcn_mfma_f32_32x32x16_bf16(af[mt][2], bg[2][nt], a0, 0, 0, 0);
        }

    float v00 = rdlanef(acc[0][0], 0);
    int k = (int)(__float_as_uint(v00) >> 23) - 127;
    float r = __uint_as_float((unsigned int)(127 - k) << 23);

#pragma unroll
    for (int mt = 0; mt < 2; mt++)
#pragma unroll
        for (int nt = 0; nt < 2; nt++) {
            int c = l31 + 32 * nt;
#pragma unroll
            for (int g = 0; g < 4; g++) {
                int a0 = 32 * mt + 8 * g + 4 * half;
                if (a0 < KK) {
                    const f32x16& Aq = acc[mt * 2 + nt];
                    unsigned int u0 = bf16bits(Aq[4 * g + 0] * r) | (bf16bits(Aq[4 * g + 1] * r) << 16);
                    unsigned int u1 = bf16bits(Aq[4 * g + 2] * r) | (bf16bits(Aq[4 * g + 3] * r) << 16);
                    *(uint2*)&Ub[c * PST + a0] = make_uint2(u0, u1);
                }
            }
        }
    return k;
}

// Variant: A read from LDS col-major slot (A[m][k] = As[k*PST + m]).
__device__ __forceinline__ int chain_product_ldsA(const bf16_t* As, bf16_t* Ub, int lane) {
    const int half = lane >> 5;
    const int l31 = lane & 31;
    f32x16 z16;
#pragma unroll
    for (int r = 0; r < 16; r++) z16[r] = 0.0f;

    bf16x8 af[2][3];
#pragma unroll
    for (int mt = 0; mt < 2; mt++) {
        int m = l31 + 32 * mt;
#pragma unroll
        for (int ks = 0; ks < 3; ks++) {
            bf16x8 f;
#pragma unroll
            for (int j = 0; j < 8; j++) {
                int k = 16 * ks + 8 * half + j;
                f[j] = (m < KK) ? As[k * PST + m] : (bf16_t)0.0f;
            }
            af[mt][ks] = f;
        }
    }
    bf16x8 bg[3][2];
#pragma unroll
    for (int ks = 0; ks < 3; ks++)
#pragma unroll
        for (int nt = 0; nt < 2; nt++)
            bg[ks][nt] = __builtin_bit_cast(bf16x8, *(const uint4*)&Ub[(l31 + 32 * nt) * PST + 16 * ks + 8 * half]);

    f32x16 acc[4];
#pragma unroll
    for (int mt = 0; mt < 2; mt++)
#pragma unroll
        for (int nt = 0; nt < 2; nt++) {
            f32x16 a0 = __builtin_amdgcn_mfma_f32_32x32x16_bf16(af[mt][0], bg[0][nt], z16, 0, 0, 0);
            a0 = __builtin_amdgcn_mfma_f32_32x32x16_bf16(af[mt][1], bg[1][nt], a0, 0, 0, 0);
            acc[mt * 2 + nt] = __builtin_amdgcn_mfma_f32_32x32x16_bf16(af[mt][2], bg[2][nt], a0, 0, 0, 0);
        }

    float v00 = rdlanef(acc[0][0], 0);
    int k = (int)(__float_as_uint(v00) >> 23) - 127;
    float r = __uint_as_float((unsigned int)(127 - k) << 23);

#pragma unroll
    for (int mt = 0; mt < 2; mt++)
#pragma unroll
        for (int nt = 0; nt < 2; nt++) {
            int c = l31 + 32 * nt;
#pragma unroll
            for (int g = 0; g < 4; g++) {
                int a0 = 32 * mt + 8 * g + 4 * half;
                if (a0 < KK) {
                    const f32x16& Aq = acc[mt * 2 + nt];
                    unsigned int u0 = bf16bits(Aq[4 * g + 0] * r) | (bf16bits(Aq[4 * g + 1] * r) << 16);
                    unsigned int u1 = bf16bits(Aq[4 * g + 2] * r) | (bf16bits(Aq[4 * g + 3] * r) << 16);
                    *(uint2*)&Ub[c * PST + a0] = make_uint2(u0, u1);
                }
            }
        }
    return k;
}

// ============ fold_final: merged fold+final — one launch ==========================
// grid B, 256 threads. Wave w serially folds its nseg/4 consecutive slots into
// Ws[w], then 4->2->1 tree + q0 + output. per = nseg/4 in {4,5,6,7,8}; fold order
// is by slot index = time order, so mixed segment lengths need no special handling.
__global__ __launch_bounds__(256) void fold_final_kernel(
    const float* __restrict__ y_pred, const bf16_t* __restrict__ ws_u,
    const int* __restrict__ ws_ls, const float* __restrict__ ws_target,
    float* __restrict__ out, int nseg) {
    const int b = blockIdx.x;
    const int tid = threadIdx.x;
    const int w = tid >> 6, lane = tid & 63;
    const int per = nseg / 4;              // 4..8

    __shared__ __align__(16) bf16_t Ws[4][64 * PST];
    __shared__ int lsp[8];
    if (tid < 8) lsp[tid] = 0;
    __syncthreads();

    {   // wave w: fold slots [base, base+per) serially (later segment on the left)
        const int base = b * nseg + per * w;
        const bf16_t* s0 = ws_u + (size_t)base * SEGELEMS;
        for (int k = 0; k < KK; k++)
            Ws[w][lane * PST + k] = (lane < KK) ? s0[(size_t)k * 48 + lane] : (bf16_t)0.0f;
        int lsk = ws_ls[base];
        for (int j = 1; j < per; j++) {
            lsk += ws_ls[base + j];
            lsk += chain_product(ws_u + (size_t)(base + j) * SEGELEMS, Ws[w], lane);
        }
        if (lane == 0) lsp[w] = lsk;
    }
    __syncthreads();
    int k1 = 0;
    if (w == 0) k1 = chain_product_ldsA(Ws[1], Ws[0], lane);        // Ws0 = W1*W0
    if (w == 2) {                                                    // Ws2 = W3*W2
        int k2 = chain_product_ldsA(Ws[3], Ws[2], lane);
        if (lane == 0) lsp[5] = k2;
    }
    __syncthreads();

    if (w == 0) {
        int k3 = chain_product_ldsA(Ws[2], Ws[0], lane);             // Ws0 = (W3W2)(W1W0)
        float L = (float)(lsp[0] + lsp[1] + lsp[2] + lsp[3] + k1 + lsp[5] + k3);

        // q0 from t=0 row
        float x0 = (lane < KK) ? y_pred[(size_t)b * TT * KK + lane] : 0.0f;
        bool ok0 = (lane >= KK) || (x0 > -1e6f);
        bool m0 = (__ballot(ok0) == ~0ull);
        float xeff = (lane < KK) ? (m0 ? x0 : 0.0f) : 0.0f;
        float c0 = rdlanef(xeff, 0);
        float q0 = (lane < KK) ? fexp(xeff - c0) : 0.0f;

        float p = 0.0f;
        if (lane < KK) {
            for (int c = 0; c < KK; c++) {
                float qc = rdlanef(q0, c);
                p = fmaf(bf2f(Ws[0][c * PST + lane]), qc, p);
            }
        }
#pragma unroll
        for (int off = 32; off; off >>= 1) p += __shfl_xor(p, off);

        // target = sum of per-block partials
        float tg = (lane < nseg) ? ws_target[b * nseg + lane] : 0.0f;
#pragma unroll
        for (int off = 32; off; off >>= 1) tg += __shfl_xor(tg, off);

        if (lane == 0) {
            out[b] = c0 + 0.6931471805599453f * (L + flog2(p)) - tg;
        }
    }
}

extern "C" void kernel_launch(void* const* d_in, const int* in_sizes, int n_in,
                              void* d_out, int out_size, void* d_ws, size_t ws_size,
                              hipStream_t stream) {
    const float* y_true = (const float*)d_in[0];
    const float* y_pred = (const float*)d_in[1];
    const float* trans = (const float*)d_in[2];
    float* out = (float*)d_out;

    // adaptive segment count (never overrun d_ws). Mixed-length tiers: nseg
    // segments = (32-nseg) x 256 steps + (2*nseg-32) x 128 steps. Needs
    // nseg*BB*SEGBYTES of U workspace. nseg=20 needs 5.93MB (known to fit:
    // r0 ran 6.32MB); 24 -> 7.11MB; 28 -> 8.29MB; 32 -> 9.47MB.
    int nseg = 16;
    if (ws_size > (size_t)WS_U_OFF) {
        size_t navail = (ws_size - (size_t)WS_U_OFF) / ((size_t)BB * SEGBYTES);
        if (navail >= 32) nseg = 32;
        else if (navail >= 28) nseg = 28;
        else if (navail >= 24) nseg = 24;
        else if (navail >= 20) nseg = 20;
    }

    float* ws_target = (float*)d_ws;                          // BB*nseg floats (<=16 KB)
    int* ws_ls = (int*)((char*)d_ws + WS_LS_OFF);             // BB*nseg ints  (<=16 KB)
    bf16_t* ws_u = (bf16_t*)((char*)d_ws + WS_U_OFF);

    fused_kernel<<<dim3(nseg, BB), 256, 0, stream>>>(
        y_true, y_pred, trans, ws_target, ws_ls, ws_u, nseg);
    fold_final_kernel<<<BB, 256, 0, stream>>>(y_pred, ws_u, ws_ls, ws_target, out, nseg);
}